// Round 10
// baseline (286.955 us; speedup 1.0000x reference)
//
#include <hip/hip_runtime.h>
#include <cstdint>
#include <cstddef>

#define BB   4
#define AA   256
#define NNB  64
#define FF   128
#define NBAS 20
#define NLAY 3
#define BA   (BB*AA)        // 1024 atoms total
#define EDG  (BA*NNB)       // 65536 edges

typedef __attribute__((ext_vector_type(8))) short bf16x8;
typedef __attribute__((ext_vector_type(4))) float f32x4;

__device__ __forceinline__ float silu_f(float x){ return x / (1.0f + __expf(-x)); }

// round-to-nearest-even f32 -> bf16 bits
__device__ __forceinline__ unsigned short f2bf(float x){
  unsigned int u = __float_as_uint(x);
  u += 0x7FFFu + ((u >> 16) & 1u);
  return (unsigned short)(u >> 16);
}
__device__ __forceinline__ unsigned int pk2(float a, float b){
  return (unsigned int)f2bf(a) | ((unsigned int)f2bf(b) << 16);
}

// ------------- weight conversion: eqf_W1, eqf_W2, eme_W1, eme_W2 (+ padded me_W) ------------
__global__ void k_cvtw(const float* __restrict__ a, const float* __restrict__ b,
                       const float* __restrict__ c, const float* __restrict__ d,
                       const float* __restrict__ me, unsigned short* __restrict__ out){
  int id = blockIdx.x*256 + threadIdx.x;
  if (id < 196608){
    int reg = id / 49152, off = id - reg*49152;
    const float* src = (reg==0)?a:(reg==1)?b:(reg==2)?c:d;
    out[id] = f2bf(src[off]);
  } else if (id < 196608 + 12288){
    int p = id - 196608;
    int l = p >> 12;            // layer
    int rem = p & 4095;
    int row = rem >> 5, k = rem & 31;
    float v = (k < NBAS) ? me[((size_t)l*FF + row)*NBAS + k] : 0.0f;
    out[id] = f2bf(v);
  }
}

// ---------------- f32 two-pass MLP core over 16 rows ----------------
__device__ __forceinline__ void mlp16(const float (*xs)[FF], float (*hs)[FF], int o,
    const float* __restrict__ W1, const float* __restrict__ b1,
    const float* __restrict__ W2, const float* __restrict__ b2, float acc[16]){
  #pragma unroll
  for (int r=0;r<16;++r) acc[r] = b1[o];
  #pragma unroll
  for (int ic=0;ic<4;++ic){
    float4 wv[8];
    #pragma unroll
    for (int j=0;j<8;++j) wv[j] = *reinterpret_cast<const float4*>(&W1[(size_t)o*FF + ic*32 + j*4]);
    #pragma unroll
    for (int r=0;r<16;++r){
      #pragma unroll
      for (int j=0;j<8;++j){
        float4 xv = *reinterpret_cast<const float4*>(&xs[r][ic*32+j*4]);
        acc[r] = fmaf(xv.x, wv[j].x, acc[r]);
        acc[r] = fmaf(xv.y, wv[j].y, acc[r]);
        acc[r] = fmaf(xv.z, wv[j].z, acc[r]);
        acc[r] = fmaf(xv.w, wv[j].w, acc[r]);
      }
    }
  }
  #pragma unroll
  for (int r=0;r<16;++r) hs[r][o] = silu_f(acc[r]);
  __syncthreads();
  #pragma unroll
  for (int r=0;r<16;++r) acc[r] = b2[o];
  #pragma unroll
  for (int ic=0;ic<4;++ic){
    float4 wv[8];
    #pragma unroll
    for (int j=0;j<8;++j) wv[j] = *reinterpret_cast<const float4*>(&W2[(size_t)o*FF + ic*32 + j*4]);
    #pragma unroll
    for (int r=0;r<16;++r){
      #pragma unroll
      for (int j=0;j<8;++j){
        float4 xv = *reinterpret_cast<const float4*>(&hs[r][ic*32+j*4]);
        acc[r] = fmaf(xv.x, wv[j].x, acc[r]);
        acc[r] = fmaf(xv.y, wv[j].y, acc[r]);
        acc[r] = fmaf(xv.z, wv[j].z, acc[r]);
        acc[r] = fmaf(xv.w, wv[j].w, acc[r]);
      }
    }
  }
}

// ------- initial node kernel: emb gather + inv_node write + 3 node MLPs (layer 0) -------
__global__ __launch_bounds__(128) void k_node3_first(
    const int* __restrict__ z, const float* __restrict__ emb, float* __restrict__ inv_node,
    const float* W1a, const float* b1a, const float* W2a, const float* b2a, float* Ya,
    const float* W1b, const float* b1b, const float* W2b, const float* b2b, float* Yb,
    const float* W1c, const float* b1c, const float* W2c, const float* b2c, float* Yc){
  const float *W1,*b1,*W2,*b2; float* Y;
  if (blockIdx.y==0){ W1=W1a;b1=b1a;W2=W2a;b2=b2a;Y=Ya; }
  else if (blockIdx.y==1){ W1=W1b;b1=b1b;W2=W2b;b2=b2b;Y=Yb; }
  else { W1=W1c;b1=b1c;W2=W2c;b2=b2c;Y=Yc; }
  __shared__ __align__(16) float xs[16][FF];
  __shared__ __align__(16) float hs[16][FF];
  const int o = threadIdx.x;
  const int row0 = blockIdx.x * 16;
  #pragma unroll
  for (int r=0;r<16;++r){
    float v = emb[(size_t)z[row0+r]*FF + o];
    xs[r][o] = v;
    if (blockIdx.y==0) inv_node[(size_t)(row0+r)*FF + o] = v;
  }
  __syncthreads();
  float acc[16];
  mlp16(xs, hs, o, W1, b1, W2, b2, acc);
  #pragma unroll
  for (int r=0;r<16;++r) Y[(size_t)(row0+r)*FF + o] = acc[r];
}

// ---------------- three node MLPs in one dispatch (layers 1,2) ----------------
__global__ __launch_bounds__(128) void k_mlp_node3(const float* __restrict__ X,
    const float* W1a, const float* b1a, const float* W2a, const float* b2a, float* Ya,
    const float* W1b, const float* b1b, const float* W2b, const float* b2b, float* Yb,
    const float* W1c, const float* b1c, const float* W2c, const float* b2c, float* Yc){
  const float *W1,*b1,*W2,*b2; float* Y;
  if (blockIdx.y==0){ W1=W1a;b1=b1a;W2=W2a;b2=b2a;Y=Ya; }
  else if (blockIdx.y==1){ W1=W1b;b1=b1b;W2=W2b;b2=b2b;Y=Yb; }
  else { W1=W1c;b1=b1c;W2=W2c;b2=b2c;Y=Yc; }
  __shared__ __align__(16) float xs[16][FF];
  __shared__ __align__(16) float hs[16][FF];
  const int o = threadIdx.x;
  const int row0 = blockIdx.x * 16;
  #pragma unroll
  for (int r=0;r<16;++r) xs[r][o] = X[(size_t)(row0+r)*FF + o];
  __syncthreads();
  float acc[16];
  mlp16(xs, hs, o, W1, b1, W2, b2, acc);
  #pragma unroll
  for (int r=0;r<16;++r) Y[(size_t)(row0+r)*FF + o] = acc[r];
}

// =====================================================================
// k_edge1: grid 512, 2 atoms (128 edges) per block.
//   phase A: inline geometry, me-MLP (MFMA swapped), inv_msg -> LDS,
//            scalg + eqF (absolute write on first).
//   phase B (ONE barrier): X frags -> regs; GEMM1-eqf -> H1 and (if
//            !first) GEMM1-eme -> H2, W1 fragments read DIRECTLY from
//            global (L2-hot, shared across all blocks; no LDS staging,
//            no extra barriers -> straight-line MFMA both paths).
// =====================================================================
__global__ __launch_bounds__(256) void k_edge1(
    const float* __restrict__ dist, const float* __restrict__ dvec,
    const float* __restrict__ maskp, const int* __restrict__ nbrs,
    const float* __restrict__ msg_node,
    const unsigned short* __restrict__ meWb, const float* __restrict__ meb,
    const float* __restrict__ eqcW,
    const unsigned short* __restrict__ W1eq, const float* __restrict__ b1eq,
    const unsigned short* __restrict__ W1me,
    unsigned short* __restrict__ H1, unsigned short* __restrict__ H2,
    float* __restrict__ scalg, float* __restrict__ eqF, int first){
  __shared__ unsigned short Xs[128*136];
  __shared__ float eqFred[4][2][3];
  const int t = threadIdx.x, w = t>>6, l = t&63;
  const int bid = blockIdx.x, a0 = bid*2;
  const int g = l&15, kg = (l>>4)<<3, r0 = (l>>4)<<2;
  const float c5 = 0.6283185307179586f;      // pi/5

  #pragma unroll
  for (int p=0;p<2;++p){
    const int atom = a0 + p;
    const int eg = atom*NNB + w*16 + g;
    const float d = dist[eg];
    const float dinv = 1.0f/(d + 1e-8f);
    const float xx = d*0.2f;
    float x2=xx*xx, x4=x2*x2, x6=x4*x2, x7=x6*xx, x8=x7*xx;
    float ct = 1.0f - 28.0f*x6 + 48.0f*x7 - 21.0f*x8;
    ct = (xx < 1.0f) ? ct : 0.0f;
    bf16x8 rfr;
    #pragma unroll
    for (int i=0;i<8;++i){
      int k = kg + i;
      float v = (k < NBAS) ? __sinf((float)(k+1)*c5*d)*dinv : 0.0f;
      rfr[i] = (short)f2bf(v);
    }
    f32x4 acc[8];
    #pragma unroll
    for (int nt=0;nt<8;++nt){
      bf16x8 wfr = *(const bf16x8*)(meWb + (nt*16 + g)*32 + kg);
      acc[nt] = __builtin_amdgcn_mfma_f32_16x16x32_bf16(wfr, rfr, f32x4{0.f,0.f,0.f,0.f}, 0,0,0);
    }
    const int bbase = (atom/AA)*AA;
    const int nbv = bbase + nbrs[eg];
    float pv = 0.f;
    #pragma unroll
    for (int nt=0;nt<8;++nt){
      int o0 = nt*16 + r0;
      float4 mb = *(const float4*)(meb + o0);
      float4 mi = *(const float4*)(msg_node + (size_t)atom*FF + o0);
      float4 mf = *(const float4*)(msg_node + (size_t)nbv*FF + o0);
      float4 ec = *(const float4*)(eqcW + o0);
      float v0 = (acc[nt][0]+mb.x)*ct*mi.x*mf.x;
      float v1 = (acc[nt][1]+mb.y)*ct*mi.y*mf.y;
      float v2 = (acc[nt][2]+mb.z)*ct*mi.z*mf.z;
      float v3 = (acc[nt][3]+mb.w)*ct*mi.w*mf.w;
      pv = fmaf(v0,ec.x, fmaf(v1,ec.y, fmaf(v2,ec.z, fmaf(v3,ec.w, pv))));
      uint2 u; u.x = pk2(v0,v1); u.y = pk2(v2,v3);
      *(uint2*)(&Xs[(p*64 + w*16 + g)*136 + o0]) = u;
    }
    pv += __shfl_xor(pv,16); pv += __shfl_xor(pv,32);
    float cf0=0.f, cf1=0.f, cf2=0.f;
    if (l < 16){
      float m  = maskp[eg];
      float s0 = pv*dvec[(size_t)eg*3+0]*dinv;
      float s1 = pv*dvec[(size_t)eg*3+1]*dinv;
      float s2 = pv*dvec[(size_t)eg*3+2]*dinv;
      float4 sv; sv.x=s0; sv.y=s1; sv.z=s2; sv.w=m;
      *(float4*)(scalg + (size_t)eg*4) = sv;
      cf0 = s0*m; cf1 = s1*m; cf2 = s2*m;
    }
    #pragma unroll
    for (int s2=1; s2<16; s2<<=1){
      cf0 += __shfl_xor(cf0,s2); cf1 += __shfl_xor(cf1,s2); cf2 += __shfl_xor(cf2,s2);
    }
    if (l == 0){ eqFred[w][p][0]=cf0; eqFred[w][p][1]=cf1; eqFred[w][p][2]=cf2; }
  }
  __syncthreads();

  // X fragments -> registers; eq_F final write
  bf16x8 xf[2][4];
  #pragma unroll
  for (int ms=0;ms<2;++ms)
    #pragma unroll
    for (int ks=0;ks<4;++ks)
      xf[ms][ks] = *(const bf16x8*)(&Xs[(w*32 + ms*16 + g)*136 + ks*32 + kg]);
  if (t < 6){
    int p = t/3, c = t - p*3;
    float s = eqFred[0][p][c]+eqFred[1][p][c]+eqFred[2][p][c]+eqFred[3][p][c];
    eqF[(a0+p)*3 + c] = first ? s : (eqF[(a0+p)*3 + c] + s);
  }

  // ---- GEMM1-eqf with global W1eq -> H1 ----
  f32x4 acc2[2][8];
  #pragma unroll
  for (int ms=0;ms<2;++ms)
    #pragma unroll
    for (int nt=0;nt<8;++nt) acc2[ms][nt] = f32x4{0.f,0.f,0.f,0.f};
  #pragma unroll
  for (int nt=0;nt<8;++nt)
    #pragma unroll
    for (int ks=0;ks<4;++ks){
      bf16x8 wfr = *(const bf16x8*)(W1eq + (nt*16+g)*FF + ks*32 + kg);
      #pragma unroll
      for (int ms=0;ms<2;++ms)
        acc2[ms][nt] = __builtin_amdgcn_mfma_f32_16x16x32_bf16(wfr, xf[ms][ks], acc2[ms][nt], 0,0,0);
    }
  #pragma unroll
  for (int ms=0;ms<2;++ms)
    #pragma unroll
    for (int nt=0;nt<8;++nt){
      int o0 = nt*16 + r0;
      float4 bb = *(const float4*)(b1eq + o0);
      uint2 u;
      u.x = pk2(silu_f(acc2[ms][nt][0]+bb.x), silu_f(acc2[ms][nt][1]+bb.y));
      u.y = pk2(silu_f(acc2[ms][nt][2]+bb.z), silu_f(acc2[ms][nt][3]+bb.w));
      *(uint2*)(H1 + (size_t)(bid*128 + w*32 + ms*16 + g)*FF + o0) = u;
    }

  if (!first){
    // ---- GEMM1-eme with global W1me -> H2 (no barrier needed) ----
    #pragma unroll
    for (int ms=0;ms<2;++ms)
      #pragma unroll
      for (int nt=0;nt<8;++nt) acc2[ms][nt] = f32x4{0.f,0.f,0.f,0.f};
    #pragma unroll
    for (int nt=0;nt<8;++nt)
      #pragma unroll
      for (int ks=0;ks<4;++ks){
        bf16x8 wfr = *(const bf16x8*)(W1me + (nt*16+g)*FF + ks*32 + kg);
        #pragma unroll
        for (int ms=0;ms<2;++ms)
          acc2[ms][nt] = __builtin_amdgcn_mfma_f32_16x16x32_bf16(wfr, xf[ms][ks], acc2[ms][nt], 0,0,0);
      }
    #pragma unroll
    for (int ms=0;ms<2;++ms)
      #pragma unroll
      for (int nt=0;nt<8;++nt){
        int o0 = nt*16 + r0;
        uint2 u;
        u.x = pk2(silu_f(acc2[ms][nt][0]), silu_f(acc2[ms][nt][1]));
        u.y = pk2(silu_f(acc2[ms][nt][2]), silu_f(acc2[ms][nt][3]));
        *(uint2*)(H2 + (size_t)(bid*128 + w*32 + ms*16 + g)*FF + o0) = u;
      }
  }
}

// =====================================================================
// k_z: grid 1024 (one atom). GEMM2-eqf (+GEMM2-eme if !first) + reductions
// + merged finalize. W2 read DIRECTLY from global (no LDS staging) ->
// LDS ~13 KB -> 8 blocks/CU.
// =====================================================================
__global__ __launch_bounds__(256) void k_z(
    const unsigned short* __restrict__ H1, const unsigned short* __restrict__ H2,
    const unsigned short* __restrict__ W2eq, const float* __restrict__ b2eq,
    const unsigned short* __restrict__ W2me,
    const float* __restrict__ scalg, const int* __restrict__ nbrs,
    const float* __restrict__ eqdrT_prev, float* __restrict__ eqdrT_next,
    const float* __restrict__ esu, const float* __restrict__ isu,
    float* __restrict__ eqf_out, float* __restrict__ eqdr,
    float* __restrict__ inv_node, int first){
  __shared__ float scal[64][4];
  __shared__ int   nbq[64];
  __shared__ float afl1[4][384];
  __shared__ float afl2[4][384];
  const int t = threadIdx.x, w = t>>6, l = t&63;
  const int atom = blockIdx.x;
  const int g = l&15, le = w*16 + g;
  const int kg = (l>>4)<<3, r0 = (l>>4)<<2;

  if (t < 64){
    float4 s = *(const float4*)(scalg + (size_t)(atom*NNB + t)*4);
    scal[t][0]=s.x; scal[t][1]=s.y; scal[t][2]=s.z; scal[t][3]=s.w;
    nbq[t] = (atom/AA)*AA + nbrs[atom*NNB + t];
  }
  bf16x8 hfr1[4];
  #pragma unroll
  for (int ks=0;ks<4;++ks)
    hfr1[ks] = *(const bf16x8*)(H1 + ((size_t)atom*NNB + le)*FF + ks*32 + kg);
  __syncthreads();
  // ---- GEMM2-eqf (global W2eq) + masked scal reduce -> afl1 ----
  f32x4 acc[8];
  #pragma unroll
  for (int nt=0;nt<8;++nt) acc[nt] = f32x4{0.f,0.f,0.f,0.f};
  #pragma unroll
  for (int nt=0;nt<8;++nt)
    #pragma unroll
    for (int ks=0;ks<4;++ks){
      bf16x8 wfr = *(const bf16x8*)(W2eq + (nt*16+g)*FF + ks*32 + kg);
      acc[nt] = __builtin_amdgcn_mfma_f32_16x16x32_bf16(hfr1[ks], wfr, acc[nt], 0,0,0);
    }
  #pragma unroll
  for (int nt=0;nt<8;++nt){
    int col = nt*16 + g;
    float bb = b2eq[col];
    float q0=0.f,q1=0.f,q2=0.f;
    #pragma unroll
    for (int r=0;r<4;++r){
      int row = w*16 + r0 + r;
      float ym = (acc[nt][r] + bb) * scal[row][3];
      q0 = fmaf(ym, scal[row][0], q0);
      q1 = fmaf(ym, scal[row][1], q1);
      q2 = fmaf(ym, scal[row][2], q2);
    }
    q0 += __shfl_xor(q0,16); q0 += __shfl_xor(q0,32);
    q1 += __shfl_xor(q1,16); q1 += __shfl_xor(q1,32);
    q2 += __shfl_xor(q2,16); q2 += __shfl_xor(q2,32);
    if (l < 16){
      afl1[w][0*128+col] = q0; afl1[w][1*128+col] = q1; afl1[w][2*128+col] = q2;
    }
  }
  if (!first){
    bf16x8 hfr2[4];
    #pragma unroll
    for (int ks=0;ks<4;++ks)
      hfr2[ks] = *(const bf16x8*)(H2 + ((size_t)atom*NNB + le)*FF + ks*32 + kg);
    // ---- GEMM2-eme (global W2me) + eqdrT_prev gather reduce -> afl2 ----
    #pragma unroll
    for (int nt=0;nt<8;++nt) acc[nt] = f32x4{0.f,0.f,0.f,0.f};
    #pragma unroll
    for (int nt=0;nt<8;++nt)
      #pragma unroll
      for (int ks=0;ks<4;++ks){
        bf16x8 wfr = *(const bf16x8*)(W2me + (nt*16+g)*FF + ks*32 + kg);
        acc[nt] = __builtin_amdgcn_mfma_f32_16x16x32_bf16(hfr2[ks], wfr, acc[nt], 0,0,0);
      }
    #pragma unroll
    for (int nt=0;nt<8;++nt){
      int col = nt*16 + g;
      float q0=0.f,q1=0.f,q2=0.f;
      #pragma unroll
      for (int r=0;r<4;++r){
        int row = w*16 + r0 + r;
        float ym = acc[nt][r] * scal[row][3];
        float4 gv = *(const float4*)(eqdrT_prev + ((size_t)nbq[row]*FF + col)*4);
        q0 = fmaf(ym, gv.x, q0);
        q1 = fmaf(ym, gv.y, q1);
        q2 = fmaf(ym, gv.z, q2);
      }
      q0 += __shfl_xor(q0,16); q0 += __shfl_xor(q0,32);
      q1 += __shfl_xor(q1,16); q1 += __shfl_xor(q1,32);
      q2 += __shfl_xor(q2,16); q2 += __shfl_xor(q2,32);
      if (l < 16){
        afl2[w][0*128+col] = q0; afl2[w][1*128+col] = q1; afl2[w][2*128+col] = q2;
      }
    }
  }
  __syncthreads();
  // ---- merged finalize ----
  for (int i=t; i<384; i+=256){
    int o = i & 127;
    float s1 = afl1[0][i]+afl1[1][i]+afl1[2][i]+afl1[3][i];
    float s2 = first ? 0.0f : (afl2[0][i]+afl2[1][i]+afl2[2][i]+afl2[3][i]);
    size_t idx = (size_t)atom*384 + i;
    float ef = first ? s1 : (eqf_out[idx] + s1);
    eqf_out[idx] = ef;
    float es = esu[(size_t)atom*FF + o];
    float v = (first ? 0.0f : eqdr[idx]) + s2 + es*s1;
    eqdr[idx] = v;
    eqdrT_next[((size_t)atom*FF + o)*4 + (i>>7)] = v;
    afl1[0][i] = ef * v;                       // reuse for cross-c sum
  }
  __syncthreads();
  if (t < 128){
    float sum3 = afl1[0][t] + afl1[0][128+t] + afl1[0][256+t];
    size_t idx = (size_t)atom*FF + t;
    inv_node[idx] = fmaf(-isu[idx], sum3, inv_node[idx]);
  }
}

extern "C" void kernel_launch(void* const* d_in, const int* in_sizes, int n_in,
                              void* d_out, int out_size, void* d_ws, size_t ws_size,
                              hipStream_t stream){
  const int*   z     = (const int*)  d_in[0];
  const int*   nbrs  = (const int*)  d_in[2];
  const float* maskp = (const float*)d_in[3];
  const float* dist  = (const float*)d_in[4];
  const float* dvec  = (const float*)d_in[5];
  const float* emb   = (const float*)d_in[6];
  const float* me_W  = (const float*)d_in[7];
  const float* me_b  = (const float*)d_in[8];
  const float* mn_W1 = (const float*)d_in[9];
  const float* mn_b1 = (const float*)d_in[10];
  const float* mn_W2 = (const float*)d_in[11];
  const float* mn_b2 = (const float*)d_in[12];
  const float* eqc_W = (const float*)d_in[13];
  const float* eqf_W1= (const float*)d_in[14];
  const float* eqf_b1= (const float*)d_in[15];
  const float* eqf_W2= (const float*)d_in[16];
  const float* eqf_b2= (const float*)d_in[17];
  const float* esu_W1= (const float*)d_in[18];
  const float* esu_b1= (const float*)d_in[19];
  const float* esu_W2= (const float*)d_in[20];
  const float* esu_b2= (const float*)d_in[21];
  const float* eme_W1= (const float*)d_in[22];
  const float* eme_W2= (const float*)d_in[23];
  const float* isu_W1= (const float*)d_in[24];
  const float* isu_b1= (const float*)d_in[25];
  const float* isu_W2= (const float*)d_in[26];
  const float* isu_b2= (const float*)d_in[27];

  float* out      = (float*)d_out;
  float* inv_node = out;                        // BA*FF   = 131072
  float* eqF      = out + 131072;               // BA*3    = 3072
  float* eqf      = out + 134144;               // BA*3*FF = 393216
  float* eqdr     = out + 527360;               // BA*3*FF = 393216

  // workspace layout (floats)
  float* w        = (float*)d_ws;
  float* msg_node = w;                          //   131,072
  float* esu_o    = w + 131072;                 //   131,072
  float* isu_o    = w + 262144;                 //   131,072
  float* scalg    = w + 393216;                 //   262,144 (EDG*4)
  float* eqdrT_A  = w + 655360;                 //   524,288 (BA*FF*4)
  float* eqdrT_B  = w + 1179648;                //   524,288
  unsigned short* wbf = (unsigned short*)(w + 1703936); // 208,896 us
  unsigned short* H1  = (unsigned short*)(w + 1808384); // EDG*FF us
  unsigned short* H2  = (unsigned short*)(w + 6002688); // EDG*FF us

  k_cvtw<<<817, 256, 0, stream>>>(eqf_W1, eqf_W2, eme_W1, eme_W2, me_W, wbf);
  k_node3_first<<<dim3(BA/16, 3), 128, 0, stream>>>(z, emb, inv_node,
      mn_W1,  mn_b1,  mn_W2,  mn_b2,  msg_node,
      esu_W1, esu_b1, esu_W2, esu_b2, esu_o,
      isu_W1, isu_b1, isu_W2, isu_b2, isu_o);

  for (int l=0; l<NLAY; ++l){
    size_t oB = (size_t)l*FF;
    const unsigned short* eqfW1b = wbf + 0*49152 + l*16384;
    const unsigned short* eqfW2b = wbf + 1*49152 + l*16384;
    const unsigned short* emeW1b = wbf + 2*49152 + l*16384;
    const unsigned short* emeW2b = wbf + 3*49152 + l*16384;
    const unsigned short* meWb   = wbf + 196608  + l*4096;
    float* dT_prev = (l & 1) ? eqdrT_B : eqdrT_A;   // unused at l==0 (first)
    float* dT_next = (l & 1) ? eqdrT_A : eqdrT_B;
    int first = (l==0);

    k_edge1<<<BA/2, 256, 0, stream>>>(dist, dvec, maskp, nbrs, msg_node,
        meWb, me_b+oB, eqc_W+oB, eqfW1b, eqf_b1+oB, emeW1b,
        H1, H2, scalg, eqF, first);
    k_z<<<BA, 256, 0, stream>>>(H1, H2, eqfW2b, eqf_b2+oB, emeW2b,
        scalg, nbrs, dT_prev, dT_next, esu_o, isu_o,
        eqf, eqdr, inv_node, first);
    if (l < NLAY-1){
      size_t oWn = (size_t)(l+1)*FF*FF, oBn = (size_t)(l+1)*FF;
      k_mlp_node3<<<dim3(BA/16, 3), 128, 0, stream>>>(inv_node,
          mn_W1+oWn,  mn_b1+oBn,  mn_W2+oWn,  mn_b2+oBn,  msg_node,
          esu_W1+oWn, esu_b1+oBn, esu_W2+oWn, esu_b2+oBn, esu_o,
          isu_W1+oWn, isu_b1+oBn, isu_W2+oWn, isu_b2+oBn, isu_o);
    }
  }
}

// Round 11
// 274.607 us; speedup vs baseline: 1.0450x; 1.0450x over previous
//
#include <hip/hip_runtime.h>
#include <cstdint>
#include <cstddef>

#define BB   4
#define AA   256
#define NNB  64
#define FF   128
#define NBAS 20
#define NLAY 3
#define BA   (BB*AA)        // 1024 atoms total
#define EDG  (BA*NNB)       // 65536 edges

typedef __attribute__((ext_vector_type(8))) short bf16x8;
typedef __attribute__((ext_vector_type(4))) float f32x4;

__device__ __forceinline__ float silu_f(float x){ return x / (1.0f + __expf(-x)); }

// round-to-nearest-even f32 -> bf16 bits
__device__ __forceinline__ unsigned short f2bf(float x){
  unsigned int u = __float_as_uint(x);
  u += 0x7FFFu + ((u >> 16) & 1u);
  return (unsigned short)(u >> 16);
}
__device__ __forceinline__ unsigned int pk2(float a, float b){
  return (unsigned int)f2bf(a) | ((unsigned int)f2bf(b) << 16);
}

// ------------- weight conversion: eqf_W1, eqf_W2, eme_W1, eme_W2 (+ padded me_W) ------------
__global__ void k_cvtw(const float* __restrict__ a, const float* __restrict__ b,
                       const float* __restrict__ c, const float* __restrict__ d,
                       const float* __restrict__ me, unsigned short* __restrict__ out){
  int id = blockIdx.x*256 + threadIdx.x;
  if (id < 196608){
    int reg = id / 49152, off = id - reg*49152;
    const float* src = (reg==0)?a:(reg==1)?b:(reg==2)?c:d;
    out[id] = f2bf(src[off]);
  } else if (id < 196608 + 12288){
    int p = id - 196608;
    int l = p >> 12;            // layer
    int rem = p & 4095;
    int row = rem >> 5, k = rem & 31;
    float v = (k < NBAS) ? me[((size_t)l*FF + row)*NBAS + k] : 0.0f;
    out[id] = f2bf(v);
  }
}

// ---------------- f32 two-pass MLP core over 16 rows ----------------
__device__ __forceinline__ void mlp16(const float (*xs)[FF], float (*hs)[FF], int o,
    const float* __restrict__ W1, const float* __restrict__ b1,
    const float* __restrict__ W2, const float* __restrict__ b2, float acc[16]){
  #pragma unroll
  for (int r=0;r<16;++r) acc[r] = b1[o];
  #pragma unroll
  for (int ic=0;ic<4;++ic){
    float4 wv[8];
    #pragma unroll
    for (int j=0;j<8;++j) wv[j] = *reinterpret_cast<const float4*>(&W1[(size_t)o*FF + ic*32 + j*4]);
    #pragma unroll
    for (int r=0;r<16;++r){
      #pragma unroll
      for (int j=0;j<8;++j){
        float4 xv = *reinterpret_cast<const float4*>(&xs[r][ic*32+j*4]);
        acc[r] = fmaf(xv.x, wv[j].x, acc[r]);
        acc[r] = fmaf(xv.y, wv[j].y, acc[r]);
        acc[r] = fmaf(xv.z, wv[j].z, acc[r]);
        acc[r] = fmaf(xv.w, wv[j].w, acc[r]);
      }
    }
  }
  #pragma unroll
  for (int r=0;r<16;++r) hs[r][o] = silu_f(acc[r]);
  __syncthreads();
  #pragma unroll
  for (int r=0;r<16;++r) acc[r] = b2[o];
  #pragma unroll
  for (int ic=0;ic<4;++ic){
    float4 wv[8];
    #pragma unroll
    for (int j=0;j<8;++j) wv[j] = *reinterpret_cast<const float4*>(&W2[(size_t)o*FF + ic*32 + j*4]);
    #pragma unroll
    for (int r=0;r<16;++r){
      #pragma unroll
      for (int j=0;j<8;++j){
        float4 xv = *reinterpret_cast<const float4*>(&hs[r][ic*32+j*4]);
        acc[r] = fmaf(xv.x, wv[j].x, acc[r]);
        acc[r] = fmaf(xv.y, wv[j].y, acc[r]);
        acc[r] = fmaf(xv.z, wv[j].z, acc[r]);
        acc[r] = fmaf(xv.w, wv[j].w, acc[r]);
      }
    }
  }
}

// ------- initial node kernel: emb gather + inv_node write + 3 node MLPs (layer 0) -------
__global__ __launch_bounds__(128) void k_node3_first(
    const int* __restrict__ z, const float* __restrict__ emb, float* __restrict__ inv_node,
    const float* W1a, const float* b1a, const float* W2a, const float* b2a, float* Ya,
    const float* W1b, const float* b1b, const float* W2b, const float* b2b, float* Yb,
    const float* W1c, const float* b1c, const float* W2c, const float* b2c, float* Yc){
  const float *W1,*b1,*W2,*b2; float* Y;
  if (blockIdx.y==0){ W1=W1a;b1=b1a;W2=W2a;b2=b2a;Y=Ya; }
  else if (blockIdx.y==1){ W1=W1b;b1=b1b;W2=W2b;b2=b2b;Y=Yb; }
  else { W1=W1c;b1=b1c;W2=W2c;b2=b2c;Y=Yc; }
  __shared__ __align__(16) float xs[16][FF];
  __shared__ __align__(16) float hs[16][FF];
  const int o = threadIdx.x;
  const int row0 = blockIdx.x * 16;
  #pragma unroll
  for (int r=0;r<16;++r){
    float v = emb[(size_t)z[row0+r]*FF + o];
    xs[r][o] = v;
    if (blockIdx.y==0) inv_node[(size_t)(row0+r)*FF + o] = v;
  }
  __syncthreads();
  float acc[16];
  mlp16(xs, hs, o, W1, b1, W2, b2, acc);
  #pragma unroll
  for (int r=0;r<16;++r) Y[(size_t)(row0+r)*FF + o] = acc[r];
}

// ---------------- three node MLPs in one dispatch (layers 1,2) ----------------
__global__ __launch_bounds__(128) void k_mlp_node3(const float* __restrict__ X,
    const float* W1a, const float* b1a, const float* W2a, const float* b2a, float* Ya,
    const float* W1b, const float* b1b, const float* W2b, const float* b2b, float* Yb,
    const float* W1c, const float* b1c, const float* W2c, const float* b2c, float* Yc){
  const float *W1,*b1,*W2,*b2; float* Y;
  if (blockIdx.y==0){ W1=W1a;b1=b1a;W2=W2a;b2=b2a;Y=Ya; }
  else if (blockIdx.y==1){ W1=W1b;b1=b1b;W2=W2b;b2=b2b;Y=Yb; }
  else { W1=W1c;b1=b1c;W2=W2c;b2=b2c;Y=Yc; }
  __shared__ __align__(16) float xs[16][FF];
  __shared__ __align__(16) float hs[16][FF];
  const int o = threadIdx.x;
  const int row0 = blockIdx.x * 16;
  #pragma unroll
  for (int r=0;r<16;++r) xs[r][o] = X[(size_t)(row0+r)*FF + o];
  __syncthreads();
  float acc[16];
  mlp16(xs, hs, o, W1, b1, W2, b2, acc);
  #pragma unroll
  for (int r=0;r<16;++r) Y[(size_t)(row0+r)*FF + o] = acc[r];
}

// =====================================================================
// k_edge1 (R9-proven): grid 512, 2 atoms (128 edges) per block.
//   phase A: inline geometry, me-MLP (MFMA swapped), inv_msg -> LDS,
//            scalg + eqF (absolute write on first).
//   phase B: X frags -> regs; W1eq staged in LDS -> GEMM1-eqf -> H1;
//            if (!first): W1me staged -> GEMM1-eme -> H2.
// =====================================================================
__global__ __launch_bounds__(256) void k_edge1(
    const float* __restrict__ dist, const float* __restrict__ dvec,
    const float* __restrict__ maskp, const int* __restrict__ nbrs,
    const float* __restrict__ msg_node,
    const unsigned short* __restrict__ meWb, const float* __restrict__ meb,
    const float* __restrict__ eqcW,
    const unsigned short* __restrict__ W1eq, const float* __restrict__ b1eq,
    const unsigned short* __restrict__ W1me,
    unsigned short* __restrict__ H1, unsigned short* __restrict__ H2,
    float* __restrict__ scalg, float* __restrict__ eqF, int first){
  __shared__ unsigned short Xs[128*136];
  __shared__ float eqFred[4][2][3];
  const int t = threadIdx.x, w = t>>6, l = t&63;
  const int bid = blockIdx.x, a0 = bid*2;
  const int g = l&15, kg = (l>>4)<<3, r0 = (l>>4)<<2;
  const float c5 = 0.6283185307179586f;      // pi/5

  #pragma unroll
  for (int p=0;p<2;++p){
    const int atom = a0 + p;
    const int eg = atom*NNB + w*16 + g;
    const float d = dist[eg];
    const float dinv = 1.0f/(d + 1e-8f);
    const float xx = d*0.2f;
    float x2=xx*xx, x4=x2*x2, x6=x4*x2, x7=x6*xx, x8=x7*xx;
    float ct = 1.0f - 28.0f*x6 + 48.0f*x7 - 21.0f*x8;
    ct = (xx < 1.0f) ? ct : 0.0f;
    bf16x8 rfr;
    #pragma unroll
    for (int i=0;i<8;++i){
      int k = kg + i;
      float v = (k < NBAS) ? __sinf((float)(k+1)*c5*d)*dinv : 0.0f;
      rfr[i] = (short)f2bf(v);
    }
    f32x4 acc[8];
    #pragma unroll
    for (int nt=0;nt<8;++nt){
      bf16x8 wfr = *(const bf16x8*)(meWb + (nt*16 + g)*32 + kg);
      acc[nt] = __builtin_amdgcn_mfma_f32_16x16x32_bf16(wfr, rfr, f32x4{0.f,0.f,0.f,0.f}, 0,0,0);
    }
    const int bbase = (atom/AA)*AA;
    const int nbv = bbase + nbrs[eg];
    float pv = 0.f;
    #pragma unroll
    for (int nt=0;nt<8;++nt){
      int o0 = nt*16 + r0;
      float4 mb = *(const float4*)(meb + o0);
      float4 mi = *(const float4*)(msg_node + (size_t)atom*FF + o0);
      float4 mf = *(const float4*)(msg_node + (size_t)nbv*FF + o0);
      float4 ec = *(const float4*)(eqcW + o0);
      float v0 = (acc[nt][0]+mb.x)*ct*mi.x*mf.x;
      float v1 = (acc[nt][1]+mb.y)*ct*mi.y*mf.y;
      float v2 = (acc[nt][2]+mb.z)*ct*mi.z*mf.z;
      float v3 = (acc[nt][3]+mb.w)*ct*mi.w*mf.w;
      pv = fmaf(v0,ec.x, fmaf(v1,ec.y, fmaf(v2,ec.z, fmaf(v3,ec.w, pv))));
      uint2 u; u.x = pk2(v0,v1); u.y = pk2(v2,v3);
      *(uint2*)(&Xs[(p*64 + w*16 + g)*136 + o0]) = u;
    }
    pv += __shfl_xor(pv,16); pv += __shfl_xor(pv,32);
    float cf0=0.f, cf1=0.f, cf2=0.f;
    if (l < 16){
      float m  = maskp[eg];
      float s0 = pv*dvec[(size_t)eg*3+0]*dinv;
      float s1 = pv*dvec[(size_t)eg*3+1]*dinv;
      float s2 = pv*dvec[(size_t)eg*3+2]*dinv;
      float4 sv; sv.x=s0; sv.y=s1; sv.z=s2; sv.w=m;
      *(float4*)(scalg + (size_t)eg*4) = sv;
      cf0 = s0*m; cf1 = s1*m; cf2 = s2*m;
    }
    #pragma unroll
    for (int s2=1; s2<16; s2<<=1){
      cf0 += __shfl_xor(cf0,s2); cf1 += __shfl_xor(cf1,s2); cf2 += __shfl_xor(cf2,s2);
    }
    if (l == 0){ eqFred[w][p][0]=cf0; eqFred[w][p][1]=cf1; eqFred[w][p][2]=cf2; }
  }
  __syncthreads();

  // X fragments -> registers; eq_F final write
  bf16x8 xf[2][4];
  #pragma unroll
  for (int ms=0;ms<2;++ms)
    #pragma unroll
    for (int ks=0;ks<4;++ks)
      xf[ms][ks] = *(const bf16x8*)(&Xs[(w*32 + ms*16 + g)*136 + ks*32 + kg]);
  if (t < 6){
    int p = t/3, c = t - p*3;
    float s = eqFred[0][p][c]+eqFred[1][p][c]+eqFred[2][p][c]+eqFred[3][p][c];
    eqF[(a0+p)*3 + c] = first ? s : (eqF[(a0+p)*3 + c] + s);
  }
  __syncthreads();

  // ---- stage W1eq into Xs; GEMM1-eqf -> H1 ----
  #pragma unroll
  for (int c=t; c<2048; c+=256){
    int row = c >> 4, ko = (c & 15) << 3;
    *(int4*)(&Xs[row*136 + ko]) = *(const int4*)(W1eq + row*FF + ko);
  }
  __syncthreads();
  f32x4 acc2[2][8];
  #pragma unroll
  for (int ms=0;ms<2;++ms)
    #pragma unroll
    for (int nt=0;nt<8;++nt) acc2[ms][nt] = f32x4{0.f,0.f,0.f,0.f};
  #pragma unroll
  for (int nt=0;nt<8;++nt)
    #pragma unroll
    for (int ks=0;ks<4;++ks){
      bf16x8 wfr = *(const bf16x8*)(&Xs[(nt*16+g)*136 + ks*32 + kg]);
      #pragma unroll
      for (int ms=0;ms<2;++ms)
        acc2[ms][nt] = __builtin_amdgcn_mfma_f32_16x16x32_bf16(wfr, xf[ms][ks], acc2[ms][nt], 0,0,0);
    }
  #pragma unroll
  for (int ms=0;ms<2;++ms)
    #pragma unroll
    for (int nt=0;nt<8;++nt){
      int o0 = nt*16 + r0;
      float4 bb = *(const float4*)(b1eq + o0);
      uint2 u;
      u.x = pk2(silu_f(acc2[ms][nt][0]+bb.x), silu_f(acc2[ms][nt][1]+bb.y));
      u.y = pk2(silu_f(acc2[ms][nt][2]+bb.z), silu_f(acc2[ms][nt][3]+bb.w));
      *(uint2*)(H1 + (size_t)(bid*128 + w*32 + ms*16 + g)*FF + o0) = u;
    }

  if (!first){
    __syncthreads();
    // ---- stage W1me into Xs; GEMM1-eme -> H2 ----
    #pragma unroll
    for (int c=t; c<2048; c+=256){
      int row = c >> 4, ko = (c & 15) << 3;
      *(int4*)(&Xs[row*136 + ko]) = *(const int4*)(W1me + row*FF + ko);
    }
    __syncthreads();
    #pragma unroll
    for (int ms=0;ms<2;++ms)
      #pragma unroll
      for (int nt=0;nt<8;++nt) acc2[ms][nt] = f32x4{0.f,0.f,0.f,0.f};
    #pragma unroll
    for (int nt=0;nt<8;++nt)
      #pragma unroll
      for (int ks=0;ks<4;++ks){
        bf16x8 wfr = *(const bf16x8*)(&Xs[(nt*16+g)*136 + ks*32 + kg]);
        #pragma unroll
        for (int ms=0;ms<2;++ms)
          acc2[ms][nt] = __builtin_amdgcn_mfma_f32_16x16x32_bf16(wfr, xf[ms][ks], acc2[ms][nt], 0,0,0);
      }
    #pragma unroll
    for (int ms=0;ms<2;++ms)
      #pragma unroll
      for (int nt=0;nt<8;++nt){
        int o0 = nt*16 + r0;
        uint2 u;
        u.x = pk2(silu_f(acc2[ms][nt][0]), silu_f(acc2[ms][nt][1]));
        u.y = pk2(silu_f(acc2[ms][nt][2]), silu_f(acc2[ms][nt][3]));
        *(uint2*)(H2 + (size_t)(bid*128 + w*32 + ms*16 + g)*FF + o0) = u;
      }
  }
}

// =====================================================================
// k_z: grid 1024 (one atom). Staging-bubble-free version:
//  - W2eq fragments prefetched to REGISTERS in one batch (no LDS, no barrier)
//  - W2me staging global loads issued at kernel START; ds_write after the
//    eqf GEMM (HBM latency hidden under compute); padded LDS read as R9.
// =====================================================================
__global__ __launch_bounds__(256) void k_z(
    const unsigned short* __restrict__ H1, const unsigned short* __restrict__ H2,
    const unsigned short* __restrict__ W2eq, const float* __restrict__ b2eq,
    const unsigned short* __restrict__ W2me,
    const float* __restrict__ scalg, const int* __restrict__ nbrs,
    const float* __restrict__ eqdrT_prev, float* __restrict__ eqdrT_next,
    const float* __restrict__ esu, const float* __restrict__ isu,
    float* __restrict__ eqf_out, float* __restrict__ eqdr,
    float* __restrict__ inv_node, int first){
  __shared__ unsigned short Wl[128*136];
  __shared__ float scal[64][4];
  __shared__ int   nbq[64];
  __shared__ float afl1[4][384];
  __shared__ float afl2[4][384];
  const int t = threadIdx.x, w = t>>6, l = t&63;
  const int atom = blockIdx.x;
  const int g = l&15, le = w*16 + g;
  const int kg = (l>>4)<<3, r0 = (l>>4)<<2;

  // ---- (a) issue W2me staging loads EARLY (latency hides under eqf GEMM) ----
  int4 wst[8];
  if (!first){
    #pragma unroll
    for (int i=0;i<8;++i)
      wst[i] = *(const int4*)(W2me + (size_t)(t + i*256)*8);
  }
  // ---- (b) W2eq fragments -> registers (32 independent loads, one batch) ----
  bf16x8 wq[8][4];
  #pragma unroll
  for (int nt=0;nt<8;++nt)
    #pragma unroll
    for (int ks=0;ks<4;++ks)
      wq[nt][ks] = *(const bf16x8*)(W2eq + (nt*16+g)*FF + ks*32 + kg);
  // ---- (c) per-atom data ----
  if (t < 64){
    float4 s = *(const float4*)(scalg + (size_t)(atom*NNB + t)*4);
    scal[t][0]=s.x; scal[t][1]=s.y; scal[t][2]=s.z; scal[t][3]=s.w;
    nbq[t] = (atom/AA)*AA + nbrs[atom*NNB + t];
  }
  bf16x8 hfr1[4], hfr2[4];
  #pragma unroll
  for (int ks=0;ks<4;++ks)
    hfr1[ks] = *(const bf16x8*)(H1 + ((size_t)atom*NNB + le)*FF + ks*32 + kg);
  if (!first){
    #pragma unroll
    for (int ks=0;ks<4;++ks)
      hfr2[ks] = *(const bf16x8*)(H2 + ((size_t)atom*NNB + le)*FF + ks*32 + kg);
  }
  __syncthreads();

  // ---- (d) GEMM2-eqf from registers + masked scal reduce -> afl1 ----
  f32x4 acc[8];
  #pragma unroll
  for (int nt=0;nt<8;++nt) acc[nt] = f32x4{0.f,0.f,0.f,0.f};
  #pragma unroll
  for (int nt=0;nt<8;++nt)
    #pragma unroll
    for (int ks=0;ks<4;++ks)
      acc[nt] = __builtin_amdgcn_mfma_f32_16x16x32_bf16(hfr1[ks], wq[nt][ks], acc[nt], 0,0,0);
  #pragma unroll
  for (int nt=0;nt<8;++nt){
    int col = nt*16 + g;
    float bb = b2eq[col];
    float q0=0.f,q1=0.f,q2=0.f;
    #pragma unroll
    for (int r=0;r<4;++r){
      int row = w*16 + r0 + r;
      float ym = (acc[nt][r] + bb) * scal[row][3];
      q0 = fmaf(ym, scal[row][0], q0);
      q1 = fmaf(ym, scal[row][1], q1);
      q2 = fmaf(ym, scal[row][2], q2);
    }
    q0 += __shfl_xor(q0,16); q0 += __shfl_xor(q0,32);
    q1 += __shfl_xor(q1,16); q1 += __shfl_xor(q1,32);
    q2 += __shfl_xor(q2,16); q2 += __shfl_xor(q2,32);
    if (l < 16){
      afl1[w][0*128+col] = q0; afl1[w][1*128+col] = q1; afl1[w][2*128+col] = q2;
    }
  }
  if (!first){
    // ---- (e) ds_write the prefetched W2me, then GEMM2-eme + gather -> afl2 ----
    #pragma unroll
    for (int i=0;i<8;++i){
      int j = t + i*256;
      int row = j >> 4, ko = (j & 15) << 3;
      *(int4*)(&Wl[row*136 + ko]) = wst[i];
    }
    __syncthreads();
    #pragma unroll
    for (int nt=0;nt<8;++nt) acc[nt] = f32x4{0.f,0.f,0.f,0.f};
    #pragma unroll
    for (int nt=0;nt<8;++nt)
      #pragma unroll
      for (int ks=0;ks<4;++ks){
        bf16x8 wfr = *(const bf16x8*)(&Wl[(nt*16+g)*136 + ks*32 + kg]);
        acc[nt] = __builtin_amdgcn_mfma_f32_16x16x32_bf16(hfr2[ks], wfr, acc[nt], 0,0,0);
      }
    #pragma unroll
    for (int nt=0;nt<8;++nt){
      int col = nt*16 + g;
      float q0=0.f,q1=0.f,q2=0.f;
      #pragma unroll
      for (int r=0;r<4;++r){
        int row = w*16 + r0 + r;
        float ym = acc[nt][r] * scal[row][3];
        float4 gv = *(const float4*)(eqdrT_prev + ((size_t)nbq[row]*FF + col)*4);
        q0 = fmaf(ym, gv.x, q0);
        q1 = fmaf(ym, gv.y, q1);
        q2 = fmaf(ym, gv.z, q2);
      }
      q0 += __shfl_xor(q0,16); q0 += __shfl_xor(q0,32);
      q1 += __shfl_xor(q1,16); q1 += __shfl_xor(q1,32);
      q2 += __shfl_xor(q2,16); q2 += __shfl_xor(q2,32);
      if (l < 16){
        afl2[w][0*128+col] = q0; afl2[w][1*128+col] = q1; afl2[w][2*128+col] = q2;
      }
    }
  }
  __syncthreads();
  // ---- merged finalize ----
  for (int i=t; i<384; i+=256){
    int o = i & 127;
    float s1 = afl1[0][i]+afl1[1][i]+afl1[2][i]+afl1[3][i];
    float s2 = first ? 0.0f : (afl2[0][i]+afl2[1][i]+afl2[2][i]+afl2[3][i]);
    size_t idx = (size_t)atom*384 + i;
    float ef = first ? s1 : (eqf_out[idx] + s1);
    eqf_out[idx] = ef;
    float es = esu[(size_t)atom*FF + o];
    float v = (first ? 0.0f : eqdr[idx]) + s2 + es*s1;
    eqdr[idx] = v;
    eqdrT_next[((size_t)atom*FF + o)*4 + (i>>7)] = v;
    afl1[0][i] = ef * v;                       // reuse for cross-c sum
  }
  __syncthreads();
  if (t < 128){
    float sum3 = afl1[0][t] + afl1[0][128+t] + afl1[0][256+t];
    size_t idx = (size_t)atom*FF + t;
    inv_node[idx] = fmaf(-isu[idx], sum3, inv_node[idx]);
  }
}

extern "C" void kernel_launch(void* const* d_in, const int* in_sizes, int n_in,
                              void* d_out, int out_size, void* d_ws, size_t ws_size,
                              hipStream_t stream){
  const int*   z     = (const int*)  d_in[0];
  const int*   nbrs  = (const int*)  d_in[2];
  const float* maskp = (const float*)d_in[3];
  const float* dist  = (const float*)d_in[4];
  const float* dvec  = (const float*)d_in[5];
  const float* emb   = (const float*)d_in[6];
  const float* me_W  = (const float*)d_in[7];
  const float* me_b  = (const float*)d_in[8];
  const float* mn_W1 = (const float*)d_in[9];
  const float* mn_b1 = (const float*)d_in[10];
  const float* mn_W2 = (const float*)d_in[11];
  const float* mn_b2 = (const float*)d_in[12];
  const float* eqc_W = (const float*)d_in[13];
  const float* eqf_W1= (const float*)d_in[14];
  const float* eqf_b1= (const float*)d_in[15];
  const float* eqf_W2= (const float*)d_in[16];
  const float* eqf_b2= (const float*)d_in[17];
  const float* esu_W1= (const float*)d_in[18];
  const float* esu_b1= (const float*)d_in[19];
  const float* esu_W2= (const float*)d_in[20];
  const float* esu_b2= (const float*)d_in[21];
  const float* eme_W1= (const float*)d_in[22];
  const float* eme_W2= (const float*)d_in[23];
  const float* isu_W1= (const float*)d_in[24];
  const float* isu_b1= (const float*)d_in[25];
  const float* isu_W2= (const float*)d_in[26];
  const float* isu_b2= (const float*)d_in[27];

  float* out      = (float*)d_out;
  float* inv_node = out;                        // BA*FF   = 131072
  float* eqF      = out + 131072;               // BA*3    = 3072
  float* eqf      = out + 134144;               // BA*3*FF = 393216
  float* eqdr     = out + 527360;               // BA*3*FF = 393216

  // workspace layout (floats)
  float* w        = (float*)d_ws;
  float* msg_node = w;                          //   131,072
  float* esu_o    = w + 131072;                 //   131,072
  float* isu_o    = w + 262144;                 //   131,072
  float* scalg    = w + 393216;                 //   262,144 (EDG*4)
  float* eqdrT_A  = w + 655360;                 //   524,288 (BA*FF*4)
  float* eqdrT_B  = w + 1179648;                //   524,288
  unsigned short* wbf = (unsigned short*)(w + 1703936); // 208,896 us
  unsigned short* H1  = (unsigned short*)(w + 1808384); // EDG*FF us
  unsigned short* H2  = (unsigned short*)(w + 6002688); // EDG*FF us

  k_cvtw<<<817, 256, 0, stream>>>(eqf_W1, eqf_W2, eme_W1, eme_W2, me_W, wbf);
  k_node3_first<<<dim3(BA/16, 3), 128, 0, stream>>>(z, emb, inv_node,
      mn_W1,  mn_b1,  mn_W2,  mn_b2,  msg_node,
      esu_W1, esu_b1, esu_W2, esu_b2, esu_o,
      isu_W1, isu_b1, isu_W2, isu_b2, isu_o);

  for (int l=0; l<NLAY; ++l){
    size_t oB = (size_t)l*FF;
    const unsigned short* eqfW1b = wbf + 0*49152 + l*16384;
    const unsigned short* eqfW2b = wbf + 1*49152 + l*16384;
    const unsigned short* emeW1b = wbf + 2*49152 + l*16384;
    const unsigned short* emeW2b = wbf + 3*49152 + l*16384;
    const unsigned short* meWb   = wbf + 196608  + l*4096;
    float* dT_prev = (l & 1) ? eqdrT_B : eqdrT_A;   // unused at l==0 (first)
    float* dT_next = (l & 1) ? eqdrT_A : eqdrT_B;
    int first = (l==0);

    k_edge1<<<BA/2, 256, 0, stream>>>(dist, dvec, maskp, nbrs, msg_node,
        meWb, me_b+oB, eqc_W+oB, eqfW1b, eqf_b1+oB, emeW1b,
        H1, H2, scalg, eqF, first);
    k_z<<<BA, 256, 0, stream>>>(H1, H2, eqfW2b, eqf_b2+oB, emeW2b,
        scalg, nbrs, dT_prev, dT_next, esu_o, isu_o,
        eqf, eqdr, inv_node, first);
    if (l < NLAY-1){
      size_t oWn = (size_t)(l+1)*FF*FF, oBn = (size_t)(l+1)*FF;
      k_mlp_node3<<<dim3(BA/16, 3), 128, 0, stream>>>(inv_node,
          mn_W1+oWn,  mn_b1+oBn,  mn_W2+oWn,  mn_b2+oBn,  msg_node,
          esu_W1+oWn, esu_b1+oBn, esu_W2+oWn, esu_b2+oBn, esu_o,
          isu_W1+oWn, isu_b1+oBn, isu_W2+oWn, isu_b2+oBn, isu_o);
    }
  }
}

// Round 12
// 218.157 us; speedup vs baseline: 1.3154x; 1.2588x over previous
//
#include <hip/hip_runtime.h>
#include <cstdint>
#include <cstddef>

#define BB   4
#define AA   256
#define NNB  64
#define FF   128
#define NBAS 20
#define NLAY 3
#define BA   (BB*AA)        // 1024 atoms total
#define EDG  (BA*NNB)       // 65536 edges

typedef __attribute__((ext_vector_type(8))) short bf16x8;
typedef __attribute__((ext_vector_type(4))) float f32x4;

__device__ __forceinline__ float silu_f(float x){ return x / (1.0f + __expf(-x)); }

// round-to-nearest-even f32 -> bf16 bits
__device__ __forceinline__ unsigned short f2bf(float x){
  unsigned int u = __float_as_uint(x);
  u += 0x7FFFu + ((u >> 16) & 1u);
  return (unsigned short)(u >> 16);
}
__device__ __forceinline__ unsigned int pk2(float a, float b){
  return (unsigned int)f2bf(a) | ((unsigned int)f2bf(b) << 16);
}

// ------------- weight conversion: eqf_W1, eqf_W2, eme_W1, eme_W2 (+ padded me_W) ------------
__global__ void k_cvtw(const float* __restrict__ a, const float* __restrict__ b,
                       const float* __restrict__ c, const float* __restrict__ d,
                       const float* __restrict__ me, unsigned short* __restrict__ out){
  int id = blockIdx.x*256 + threadIdx.x;
  if (id < 196608){
    int reg = id / 49152, off = id - reg*49152;
    const float* src = (reg==0)?a:(reg==1)?b:(reg==2)?c:d;
    out[id] = f2bf(src[off]);
  } else if (id < 196608 + 12288){
    int p = id - 196608;
    int l = p >> 12;            // layer
    int rem = p & 4095;
    int row = rem >> 5, k = rem & 31;
    float v = (k < NBAS) ? me[((size_t)l*FF + row)*NBAS + k] : 0.0f;
    out[id] = f2bf(v);
  }
}

// ---------------- f32 two-pass MLP core over 16 rows ----------------
__device__ __forceinline__ void mlp16(const float (*xs)[FF], float (*hs)[FF], int o,
    const float* __restrict__ W1, const float* __restrict__ b1,
    const float* __restrict__ W2, const float* __restrict__ b2, float acc[16]){
  #pragma unroll
  for (int r=0;r<16;++r) acc[r] = b1[o];
  #pragma unroll
  for (int ic=0;ic<4;++ic){
    float4 wv[8];
    #pragma unroll
    for (int j=0;j<8;++j) wv[j] = *reinterpret_cast<const float4*>(&W1[(size_t)o*FF + ic*32 + j*4]);
    #pragma unroll
    for (int r=0;r<16;++r){
      #pragma unroll
      for (int j=0;j<8;++j){
        float4 xv = *reinterpret_cast<const float4*>(&xs[r][ic*32+j*4]);
        acc[r] = fmaf(xv.x, wv[j].x, acc[r]);
        acc[r] = fmaf(xv.y, wv[j].y, acc[r]);
        acc[r] = fmaf(xv.z, wv[j].z, acc[r]);
        acc[r] = fmaf(xv.w, wv[j].w, acc[r]);
      }
    }
  }
  #pragma unroll
  for (int r=0;r<16;++r) hs[r][o] = silu_f(acc[r]);
  __syncthreads();
  #pragma unroll
  for (int r=0;r<16;++r) acc[r] = b2[o];
  #pragma unroll
  for (int ic=0;ic<4;++ic){
    float4 wv[8];
    #pragma unroll
    for (int j=0;j<8;++j) wv[j] = *reinterpret_cast<const float4*>(&W2[(size_t)o*FF + ic*32 + j*4]);
    #pragma unroll
    for (int r=0;r<16;++r){
      #pragma unroll
      for (int j=0;j<8;++j){
        float4 xv = *reinterpret_cast<const float4*>(&hs[r][ic*32+j*4]);
        acc[r] = fmaf(xv.x, wv[j].x, acc[r]);
        acc[r] = fmaf(xv.y, wv[j].y, acc[r]);
        acc[r] = fmaf(xv.z, wv[j].z, acc[r]);
        acc[r] = fmaf(xv.w, wv[j].w, acc[r]);
      }
    }
  }
}

// ------- initial node kernel: emb gather + inv_node write + 3 node MLPs (layer 0) -------
__global__ __launch_bounds__(128) void k_node3_first(
    const int* __restrict__ z, const float* __restrict__ emb, float* __restrict__ inv_node,
    const float* W1a, const float* b1a, const float* W2a, const float* b2a, float* Ya,
    const float* W1b, const float* b1b, const float* W2b, const float* b2b, float* Yb,
    const float* W1c, const float* b1c, const float* W2c, const float* b2c, float* Yc){
  const float *W1,*b1,*W2,*b2; float* Y;
  if (blockIdx.y==0){ W1=W1a;b1=b1a;W2=W2a;b2=b2a;Y=Ya; }
  else if (blockIdx.y==1){ W1=W1b;b1=b1b;W2=W2b;b2=b2b;Y=Yb; }
  else { W1=W1c;b1=b1c;W2=W2c;b2=b2c;Y=Yc; }
  __shared__ __align__(16) float xs[16][FF];
  __shared__ __align__(16) float hs[16][FF];
  const int o = threadIdx.x;
  const int row0 = blockIdx.x * 16;
  #pragma unroll
  for (int r=0;r<16;++r){
    float v = emb[(size_t)z[row0+r]*FF + o];
    xs[r][o] = v;
    if (blockIdx.y==0) inv_node[(size_t)(row0+r)*FF + o] = v;
  }
  __syncthreads();
  float acc[16];
  mlp16(xs, hs, o, W1, b1, W2, b2, acc);
  #pragma unroll
  for (int r=0;r<16;++r) Y[(size_t)(row0+r)*FF + o] = acc[r];
}

// ---------------- three node MLPs in one dispatch (layers 1,2) ----------------
__global__ __launch_bounds__(128) void k_mlp_node3(const float* __restrict__ X,
    const float* W1a, const float* b1a, const float* W2a, const float* b2a, float* Ya,
    const float* W1b, const float* b1b, const float* W2b, const float* b2b, float* Yb,
    const float* W1c, const float* b1c, const float* W2c, const float* b2c, float* Yc){
  const float *W1,*b1,*W2,*b2; float* Y;
  if (blockIdx.y==0){ W1=W1a;b1=b1a;W2=W2a;b2=b2a;Y=Ya; }
  else if (blockIdx.y==1){ W1=W1b;b1=b1b;W2=W2b;b2=b2b;Y=Yb; }
  else { W1=W1c;b1=b1c;W2=W2c;b2=b2c;Y=Yc; }
  __shared__ __align__(16) float xs[16][FF];
  __shared__ __align__(16) float hs[16][FF];
  const int o = threadIdx.x;
  const int row0 = blockIdx.x * 16;
  #pragma unroll
  for (int r=0;r<16;++r) xs[r][o] = X[(size_t)(row0+r)*FF + o];
  __syncthreads();
  float acc[16];
  mlp16(xs, hs, o, W1, b1, W2, b2, acc);
  #pragma unroll
  for (int r=0;r<16;++r) Y[(size_t)(row0+r)*FF + o] = acc[r];
}

// =====================================================================
// k_edge1 (R9-proven): grid 512, 2 atoms (128 edges) per block.
// =====================================================================
__global__ __launch_bounds__(256) void k_edge1(
    const float* __restrict__ dist, const float* __restrict__ dvec,
    const float* __restrict__ maskp, const int* __restrict__ nbrs,
    const float* __restrict__ msg_node,
    const unsigned short* __restrict__ meWb, const float* __restrict__ meb,
    const float* __restrict__ eqcW,
    const unsigned short* __restrict__ W1eq, const float* __restrict__ b1eq,
    const unsigned short* __restrict__ W1me,
    unsigned short* __restrict__ H1, unsigned short* __restrict__ H2,
    float* __restrict__ scalg, float* __restrict__ eqF, int first){
  __shared__ unsigned short Xs[128*136];
  __shared__ float eqFred[4][2][3];
  const int t = threadIdx.x, w = t>>6, l = t&63;
  const int bid = blockIdx.x, a0 = bid*2;
  const int g = l&15, kg = (l>>4)<<3, r0 = (l>>4)<<2;
  const float c5 = 0.6283185307179586f;      // pi/5

  #pragma unroll
  for (int p=0;p<2;++p){
    const int atom = a0 + p;
    const int eg = atom*NNB + w*16 + g;
    const float d = dist[eg];
    const float dinv = 1.0f/(d + 1e-8f);
    const float xx = d*0.2f;
    float x2=xx*xx, x4=x2*x2, x6=x4*x2, x7=x6*xx, x8=x7*xx;
    float ct = 1.0f - 28.0f*x6 + 48.0f*x7 - 21.0f*x8;
    ct = (xx < 1.0f) ? ct : 0.0f;
    bf16x8 rfr;
    #pragma unroll
    for (int i=0;i<8;++i){
      int k = kg + i;
      float v = (k < NBAS) ? __sinf((float)(k+1)*c5*d)*dinv : 0.0f;
      rfr[i] = (short)f2bf(v);
    }
    f32x4 acc[8];
    #pragma unroll
    for (int nt=0;nt<8;++nt){
      bf16x8 wfr = *(const bf16x8*)(meWb + (nt*16 + g)*32 + kg);
      acc[nt] = __builtin_amdgcn_mfma_f32_16x16x32_bf16(wfr, rfr, f32x4{0.f,0.f,0.f,0.f}, 0,0,0);
    }
    const int bbase = (atom/AA)*AA;
    const int nbv = bbase + nbrs[eg];
    float pv = 0.f;
    #pragma unroll
    for (int nt=0;nt<8;++nt){
      int o0 = nt*16 + r0;
      float4 mb = *(const float4*)(meb + o0);
      float4 mi = *(const float4*)(msg_node + (size_t)atom*FF + o0);
      float4 mf = *(const float4*)(msg_node + (size_t)nbv*FF + o0);
      float4 ec = *(const float4*)(eqcW + o0);
      float v0 = (acc[nt][0]+mb.x)*ct*mi.x*mf.x;
      float v1 = (acc[nt][1]+mb.y)*ct*mi.y*mf.y;
      float v2 = (acc[nt][2]+mb.z)*ct*mi.z*mf.z;
      float v3 = (acc[nt][3]+mb.w)*ct*mi.w*mf.w;
      pv = fmaf(v0,ec.x, fmaf(v1,ec.y, fmaf(v2,ec.z, fmaf(v3,ec.w, pv))));
      uint2 u; u.x = pk2(v0,v1); u.y = pk2(v2,v3);
      *(uint2*)(&Xs[(p*64 + w*16 + g)*136 + o0]) = u;
    }
    pv += __shfl_xor(pv,16); pv += __shfl_xor(pv,32);
    float cf0=0.f, cf1=0.f, cf2=0.f;
    if (l < 16){
      float m  = maskp[eg];
      float s0 = pv*dvec[(size_t)eg*3+0]*dinv;
      float s1 = pv*dvec[(size_t)eg*3+1]*dinv;
      float s2 = pv*dvec[(size_t)eg*3+2]*dinv;
      float4 sv; sv.x=s0; sv.y=s1; sv.z=s2; sv.w=m;
      *(float4*)(scalg + (size_t)eg*4) = sv;
      cf0 = s0*m; cf1 = s1*m; cf2 = s2*m;
    }
    #pragma unroll
    for (int s2=1; s2<16; s2<<=1){
      cf0 += __shfl_xor(cf0,s2); cf1 += __shfl_xor(cf1,s2); cf2 += __shfl_xor(cf2,s2);
    }
    if (l == 0){ eqFred[w][p][0]=cf0; eqFred[w][p][1]=cf1; eqFred[w][p][2]=cf2; }
  }
  __syncthreads();

  // X fragments -> registers; eq_F final write
  bf16x8 xf[2][4];
  #pragma unroll
  for (int ms=0;ms<2;++ms)
    #pragma unroll
    for (int ks=0;ks<4;++ks)
      xf[ms][ks] = *(const bf16x8*)(&Xs[(w*32 + ms*16 + g)*136 + ks*32 + kg]);
  if (t < 6){
    int p = t/3, c = t - p*3;
    float s = eqFred[0][p][c]+eqFred[1][p][c]+eqFred[2][p][c]+eqFred[3][p][c];
    eqF[(a0+p)*3 + c] = first ? s : (eqF[(a0+p)*3 + c] + s);
  }
  __syncthreads();

  // ---- stage W1eq into Xs; GEMM1-eqf -> H1 ----
  #pragma unroll
  for (int c=t; c<2048; c+=256){
    int row = c >> 4, ko = (c & 15) << 3;
    *(int4*)(&Xs[row*136 + ko]) = *(const int4*)(W1eq + row*FF + ko);
  }
  __syncthreads();
  f32x4 acc2[2][8];
  #pragma unroll
  for (int ms=0;ms<2;++ms)
    #pragma unroll
    for (int nt=0;nt<8;++nt) acc2[ms][nt] = f32x4{0.f,0.f,0.f,0.f};
  #pragma unroll
  for (int nt=0;nt<8;++nt)
    #pragma unroll
    for (int ks=0;ks<4;++ks){
      bf16x8 wfr = *(const bf16x8*)(&Xs[(nt*16+g)*136 + ks*32 + kg]);
      #pragma unroll
      for (int ms=0;ms<2;++ms)
        acc2[ms][nt] = __builtin_amdgcn_mfma_f32_16x16x32_bf16(wfr, xf[ms][ks], acc2[ms][nt], 0,0,0);
    }
  #pragma unroll
  for (int ms=0;ms<2;++ms)
    #pragma unroll
    for (int nt=0;nt<8;++nt){
      int o0 = nt*16 + r0;
      float4 bb = *(const float4*)(b1eq + o0);
      uint2 u;
      u.x = pk2(silu_f(acc2[ms][nt][0]+bb.x), silu_f(acc2[ms][nt][1]+bb.y));
      u.y = pk2(silu_f(acc2[ms][nt][2]+bb.z), silu_f(acc2[ms][nt][3]+bb.w));
      *(uint2*)(H1 + (size_t)(bid*128 + w*32 + ms*16 + g)*FF + o0) = u;
    }

  if (!first){
    __syncthreads();
    // ---- stage W1me into Xs; GEMM1-eme -> H2 ----
    #pragma unroll
    for (int c=t; c<2048; c+=256){
      int row = c >> 4, ko = (c & 15) << 3;
      *(int4*)(&Xs[row*136 + ko]) = *(const int4*)(W1me + row*FF + ko);
    }
    __syncthreads();
    #pragma unroll
    for (int ms=0;ms<2;++ms)
      #pragma unroll
      for (int nt=0;nt<8;++nt) acc2[ms][nt] = f32x4{0.f,0.f,0.f,0.f};
    #pragma unroll
    for (int nt=0;nt<8;++nt)
      #pragma unroll
      for (int ks=0;ks<4;++ks){
        bf16x8 wfr = *(const bf16x8*)(&Xs[(nt*16+g)*136 + ks*32 + kg]);
        #pragma unroll
        for (int ms=0;ms<2;++ms)
          acc2[ms][nt] = __builtin_amdgcn_mfma_f32_16x16x32_bf16(wfr, xf[ms][ks], acc2[ms][nt], 0,0,0);
      }
    #pragma unroll
    for (int ms=0;ms<2;++ms)
      #pragma unroll
      for (int nt=0;nt<8;++nt){
        int o0 = nt*16 + r0;
        uint2 u;
        u.x = pk2(silu_f(acc2[ms][nt][0]), silu_f(acc2[ms][nt][1]));
        u.y = pk2(silu_f(acc2[ms][nt][2]), silu_f(acc2[ms][nt][3]));
        *(uint2*)(H2 + (size_t)(bid*128 + w*32 + ms*16 + g)*FF + o0) = u;
      }
  }
}

// =====================================================================
// k_z: grid 512, TWO atoms per block (amortize W staging over 128 rows).
// Wave w handles rows w*32..w*32+31 (2 m-subtiles); atom p = w>>1.
// Sequential W2eq / W2me LDS staging exactly as R9 (proven mechanism).
// =====================================================================
__global__ __launch_bounds__(256) void k_z(
    const unsigned short* __restrict__ H1, const unsigned short* __restrict__ H2,
    const unsigned short* __restrict__ W2eq, const float* __restrict__ b2eq,
    const unsigned short* __restrict__ W2me,
    const float* __restrict__ scalg, const int* __restrict__ nbrs,
    const float* __restrict__ eqdrT_prev, float* __restrict__ eqdrT_next,
    const float* __restrict__ esu, const float* __restrict__ isu,
    float* __restrict__ eqf_out, float* __restrict__ eqdr,
    float* __restrict__ inv_node, int first){
  __shared__ unsigned short Wl[128*136];        // 34.8 KB
  __shared__ float scal[128][4];
  __shared__ int   nbq[128];
  __shared__ float afl1[4][384];
  __shared__ float afl2[4][384];
  __shared__ float prod[2][384];
  const int t = threadIdx.x, w = t>>6, l = t&63;
  const int bid = blockIdx.x, a0 = bid*2;
  const int g = l&15;
  const int kg = (l>>4)<<3, r0 = (l>>4)<<2;

  if (t < 128){
    int e2 = a0*NNB + t;
    float4 s = *(const float4*)(scalg + (size_t)e2*4);
    scal[t][0]=s.x; scal[t][1]=s.y; scal[t][2]=s.z; scal[t][3]=s.w;
    int atomt = a0 + (t>>6);
    nbq[t] = (atomt/AA)*AA + nbrs[e2];
  }
  bf16x8 hfr1[2][4];
  #pragma unroll
  for (int ms=0;ms<2;++ms)
    #pragma unroll
    for (int ks=0;ks<4;++ks)
      hfr1[ms][ks] = *(const bf16x8*)(H1 + (size_t)(bid*128 + w*32 + ms*16 + g)*FF + ks*32 + kg);
  // ---- stage W2eq; GEMM2-eqf + masked scal reduce -> afl1 ----
  #pragma unroll
  for (int c=t; c<2048; c+=256){
    int row = c >> 4, ko = (c & 15) << 3;
    *(int4*)(&Wl[row*136 + ko]) = *(const int4*)(W2eq + row*FF + ko);
  }
  __syncthreads();
  f32x4 acc[2][8];
  #pragma unroll
  for (int ms=0;ms<2;++ms)
    #pragma unroll
    for (int nt=0;nt<8;++nt) acc[ms][nt] = f32x4{0.f,0.f,0.f,0.f};
  #pragma unroll
  for (int nt=0;nt<8;++nt)
    #pragma unroll
    for (int ks=0;ks<4;++ks){
      bf16x8 wfr = *(const bf16x8*)(&Wl[(nt*16+g)*136 + ks*32 + kg]);
      #pragma unroll
      for (int ms=0;ms<2;++ms)
        acc[ms][nt] = __builtin_amdgcn_mfma_f32_16x16x32_bf16(hfr1[ms][ks], wfr, acc[ms][nt], 0,0,0);
    }
  #pragma unroll
  for (int nt=0;nt<8;++nt){
    int col = nt*16 + g;
    float bb = b2eq[col];
    float q0=0.f,q1=0.f,q2=0.f;
    #pragma unroll
    for (int ms=0;ms<2;++ms)
      #pragma unroll
      for (int r=0;r<4;++r){
        int row = w*32 + ms*16 + r0 + r;
        float ym = (acc[ms][nt][r] + bb) * scal[row][3];
        q0 = fmaf(ym, scal[row][0], q0);
        q1 = fmaf(ym, scal[row][1], q1);
        q2 = fmaf(ym, scal[row][2], q2);
      }
    q0 += __shfl_xor(q0,16); q0 += __shfl_xor(q0,32);
    q1 += __shfl_xor(q1,16); q1 += __shfl_xor(q1,32);
    q2 += __shfl_xor(q2,16); q2 += __shfl_xor(q2,32);
    if (l < 16){
      afl1[w][0*128+col] = q0; afl1[w][1*128+col] = q1; afl1[w][2*128+col] = q2;
    }
  }
  if (!first){
    bf16x8 hfr2[2][4];
    #pragma unroll
    for (int ms=0;ms<2;++ms)
      #pragma unroll
      for (int ks=0;ks<4;++ks)
        hfr2[ms][ks] = *(const bf16x8*)(H2 + (size_t)(bid*128 + w*32 + ms*16 + g)*FF + ks*32 + kg);
    __syncthreads();
    // ---- stage W2me; GEMM2-eme + eqdrT_prev gather reduce -> afl2 ----
    #pragma unroll
    for (int c=t; c<2048; c+=256){
      int row = c >> 4, ko = (c & 15) << 3;
      *(int4*)(&Wl[row*136 + ko]) = *(const int4*)(W2me + row*FF + ko);
    }
    __syncthreads();
    #pragma unroll
    for (int ms=0;ms<2;++ms)
      #pragma unroll
      for (int nt=0;nt<8;++nt) acc[ms][nt] = f32x4{0.f,0.f,0.f,0.f};
    #pragma unroll
    for (int nt=0;nt<8;++nt)
      #pragma unroll
      for (int ks=0;ks<4;++ks){
        bf16x8 wfr = *(const bf16x8*)(&Wl[(nt*16+g)*136 + ks*32 + kg]);
        #pragma unroll
        for (int ms=0;ms<2;++ms)
          acc[ms][nt] = __builtin_amdgcn_mfma_f32_16x16x32_bf16(hfr2[ms][ks], wfr, acc[ms][nt], 0,0,0);
      }
    #pragma unroll
    for (int nt=0;nt<8;++nt){
      int col = nt*16 + g;
      float q0=0.f,q1=0.f,q2=0.f;
      #pragma unroll
      for (int ms=0;ms<2;++ms)
        #pragma unroll
        for (int r=0;r<4;++r){
          int row = w*32 + ms*16 + r0 + r;
          float ym = acc[ms][nt][r] * scal[row][3];
          float4 gv = *(const float4*)(eqdrT_prev + ((size_t)nbq[row]*FF + col)*4);
          q0 = fmaf(ym, gv.x, q0);
          q1 = fmaf(ym, gv.y, q1);
          q2 = fmaf(ym, gv.z, q2);
        }
      q0 += __shfl_xor(q0,16); q0 += __shfl_xor(q0,32);
      q1 += __shfl_xor(q1,16); q1 += __shfl_xor(q1,32);
      q2 += __shfl_xor(q2,16); q2 += __shfl_xor(q2,32);
      if (l < 16){
        afl2[w][0*128+col] = q0; afl2[w][1*128+col] = q1; afl2[w][2*128+col] = q2;
      }
    }
  }
  __syncthreads();
  // ---- merged finalize for both atoms (768 elems) ----
  for (int i=t; i<768; i+=256){
    int p = (i >= 384) ? 1 : 0;
    int j = i - p*384;
    int o = j & 127;
    int c = j >> 7;
    float s1 = afl1[2*p][j] + afl1[2*p+1][j];
    float s2 = first ? 0.0f : (afl2[2*p][j] + afl2[2*p+1][j]);
    size_t idx = (size_t)(a0+p)*384 + j;
    float ef = first ? s1 : (eqf_out[idx] + s1);
    eqf_out[idx] = ef;
    float es = esu[(size_t)(a0+p)*FF + o];
    float v = (first ? 0.0f : eqdr[idx]) + s2 + es*s1;
    eqdr[idx] = v;
    eqdrT_next[((size_t)(a0+p)*FF + o)*4 + c] = v;
    prod[p][j] = ef * v;
  }
  __syncthreads();
  {
    int p = t >> 7, o = t & 127;
    float sum3 = prod[p][o] + prod[p][128+o] + prod[p][256+o];
    size_t idx = (size_t)(a0+p)*FF + o;
    inv_node[idx] = fmaf(-isu[idx], sum3, inv_node[idx]);
  }
}

extern "C" void kernel_launch(void* const* d_in, const int* in_sizes, int n_in,
                              void* d_out, int out_size, void* d_ws, size_t ws_size,
                              hipStream_t stream){
  const int*   z     = (const int*)  d_in[0];
  const int*   nbrs  = (const int*)  d_in[2];
  const float* maskp = (const float*)d_in[3];
  const float* dist  = (const float*)d_in[4];
  const float* dvec  = (const float*)d_in[5];
  const float* emb   = (const float*)d_in[6];
  const float* me_W  = (const float*)d_in[7];
  const float* me_b  = (const float*)d_in[8];
  const float* mn_W1 = (const float*)d_in[9];
  const float* mn_b1 = (const float*)d_in[10];
  const float* mn_W2 = (const float*)d_in[11];
  const float* mn_b2 = (const float*)d_in[12];
  const float* eqc_W = (const float*)d_in[13];
  const float* eqf_W1= (const float*)d_in[14];
  const float* eqf_b1= (const float*)d_in[15];
  const float* eqf_W2= (const float*)d_in[16];
  const float* eqf_b2= (const float*)d_in[17];
  const float* esu_W1= (const float*)d_in[18];
  const float* esu_b1= (const float*)d_in[19];
  const float* esu_W2= (const float*)d_in[20];
  const float* esu_b2= (const float*)d_in[21];
  const float* eme_W1= (const float*)d_in[22];
  const float* eme_W2= (const float*)d_in[23];
  const float* isu_W1= (const float*)d_in[24];
  const float* isu_b1= (const float*)d_in[25];
  const float* isu_W2= (const float*)d_in[26];
  const float* isu_b2= (const float*)d_in[27];

  float* out      = (float*)d_out;
  float* inv_node = out;                        // BA*FF   = 131072
  float* eqF      = out + 131072;               // BA*3    = 3072
  float* eqf      = out + 134144;               // BA*3*FF = 393216
  float* eqdr     = out + 527360;               // BA*3*FF = 393216

  // workspace layout (floats)
  float* w        = (float*)d_ws;
  float* msg_node = w;                          //   131,072
  float* esu_o    = w + 131072;                 //   131,072
  float* isu_o    = w + 262144;                 //   131,072
  float* scalg    = w + 393216;                 //   262,144 (EDG*4)
  float* eqdrT_A  = w + 655360;                 //   524,288 (BA*FF*4)
  float* eqdrT_B  = w + 1179648;                //   524,288
  unsigned short* wbf = (unsigned short*)(w + 1703936); // 208,896 us
  unsigned short* H1  = (unsigned short*)(w + 1808384); // EDG*FF us
  unsigned short* H2  = (unsigned short*)(w + 6002688); // EDG*FF us

  k_cvtw<<<817, 256, 0, stream>>>(eqf_W1, eqf_W2, eme_W1, eme_W2, me_W, wbf);
  k_node3_first<<<dim3(BA/16, 3), 128, 0, stream>>>(z, emb, inv_node,
      mn_W1,  mn_b1,  mn_W2,  mn_b2,  msg_node,
      esu_W1, esu_b1, esu_W2, esu_b2, esu_o,
      isu_W1, isu_b1, isu_W2, isu_b2, isu_o);

  for (int l=0; l<NLAY; ++l){
    size_t oB = (size_t)l*FF;
    const unsigned short* eqfW1b = wbf + 0*49152 + l*16384;
    const unsigned short* eqfW2b = wbf + 1*49152 + l*16384;
    const unsigned short* emeW1b = wbf + 2*49152 + l*16384;
    const unsigned short* emeW2b = wbf + 3*49152 + l*16384;
    const unsigned short* meWb   = wbf + 196608  + l*4096;
    float* dT_prev = (l & 1) ? eqdrT_B : eqdrT_A;   // unused at l==0 (first)
    float* dT_next = (l & 1) ? eqdrT_A : eqdrT_B;
    int first = (l==0);

    k_edge1<<<BA/2, 256, 0, stream>>>(dist, dvec, maskp, nbrs, msg_node,
        meWb, me_b+oB, eqc_W+oB, eqfW1b, eqf_b1+oB, emeW1b,
        H1, H2, scalg, eqF, first);
    k_z<<<BA/2, 256, 0, stream>>>(H1, H2, eqfW2b, eqf_b2+oB, emeW2b,
        scalg, nbrs, dT_prev, dT_next, esu_o, isu_o,
        eqf, eqdr, inv_node, first);
    if (l < NLAY-1){
      size_t oWn = (size_t)(l+1)*FF*FF, oBn = (size_t)(l+1)*FF;
      k_mlp_node3<<<dim3(BA/16, 3), 128, 0, stream>>>(inv_node,
          mn_W1+oWn,  mn_b1+oBn,  mn_W2+oWn,  mn_b2+oBn,  msg_node,
          esu_W1+oWn, esu_b1+oBn, esu_W2+oWn, esu_b2+oBn, esu_o,
          isu_W1+oWn, isu_b1+oBn, isu_W2+oWn, isu_b2+oBn, isu_o);
    }
  }
}

// Round 13
// 203.308 us; speedup vs baseline: 1.4114x; 1.0730x over previous
//
#include <hip/hip_runtime.h>
#include <cstdint>
#include <cstddef>

#define BB   4
#define AA   256
#define NNB  64
#define FF   128
#define NBAS 20
#define NLAY 3
#define BA   (BB*AA)        // 1024 atoms total
#define EDG  (BA*NNB)       // 65536 edges

typedef __attribute__((ext_vector_type(8))) short bf16x8;
typedef __attribute__((ext_vector_type(4))) float f32x4;

__device__ __forceinline__ float silu_f(float x){ return x / (1.0f + __expf(-x)); }

// round-to-nearest-even f32 -> bf16 bits
__device__ __forceinline__ unsigned short f2bf(float x){
  unsigned int u = __float_as_uint(x);
  u += 0x7FFFu + ((u >> 16) & 1u);
  return (unsigned short)(u >> 16);
}
__device__ __forceinline__ unsigned int pk2(float a, float b){
  return (unsigned int)f2bf(a) | ((unsigned int)f2bf(b) << 16);
}

// ------------- weight conversion: eqf_W1, eqf_W2, eme_W1, eme_W2 (+ padded me_W) ------------
__global__ void k_cvtw(const float* __restrict__ a, const float* __restrict__ b,
                       const float* __restrict__ c, const float* __restrict__ d,
                       const float* __restrict__ me, unsigned short* __restrict__ out){
  int id = blockIdx.x*256 + threadIdx.x;
  if (id < 196608){
    int reg = id / 49152, off = id - reg*49152;
    const float* src = (reg==0)?a:(reg==1)?b:(reg==2)?c:d;
    out[id] = f2bf(src[off]);
  } else if (id < 196608 + 12288){
    int p = id - 196608;
    int l = p >> 12;            // layer
    int rem = p & 4095;
    int row = rem >> 5, k = rem & 31;
    float v = (k < NBAS) ? me[((size_t)l*FF + row)*NBAS + k] : 0.0f;
    out[id] = f2bf(v);
  }
}

// ---------------- f32 two-pass MLP core over 16 rows ----------------
__device__ __forceinline__ void mlp16(const float (*xs)[FF], float (*hs)[FF], int o,
    const float* __restrict__ W1, const float* __restrict__ b1,
    const float* __restrict__ W2, const float* __restrict__ b2, float acc[16]){
  #pragma unroll
  for (int r=0;r<16;++r) acc[r] = b1[o];
  #pragma unroll
  for (int ic=0;ic<4;++ic){
    float4 wv[8];
    #pragma unroll
    for (int j=0;j<8;++j) wv[j] = *reinterpret_cast<const float4*>(&W1[(size_t)o*FF + ic*32 + j*4]);
    #pragma unroll
    for (int r=0;r<16;++r){
      #pragma unroll
      for (int j=0;j<8;++j){
        float4 xv = *reinterpret_cast<const float4*>(&xs[r][ic*32+j*4]);
        acc[r] = fmaf(xv.x, wv[j].x, acc[r]);
        acc[r] = fmaf(xv.y, wv[j].y, acc[r]);
        acc[r] = fmaf(xv.z, wv[j].z, acc[r]);
        acc[r] = fmaf(xv.w, wv[j].w, acc[r]);
      }
    }
  }
  #pragma unroll
  for (int r=0;r<16;++r) hs[r][o] = silu_f(acc[r]);
  __syncthreads();
  #pragma unroll
  for (int r=0;r<16;++r) acc[r] = b2[o];
  #pragma unroll
  for (int ic=0;ic<4;++ic){
    float4 wv[8];
    #pragma unroll
    for (int j=0;j<8;++j) wv[j] = *reinterpret_cast<const float4*>(&W2[(size_t)o*FF + ic*32 + j*4]);
    #pragma unroll
    for (int r=0;r<16;++r){
      #pragma unroll
      for (int j=0;j<8;++j){
        float4 xv = *reinterpret_cast<const float4*>(&hs[r][ic*32+j*4]);
        acc[r] = fmaf(xv.x, wv[j].x, acc[r]);
        acc[r] = fmaf(xv.y, wv[j].y, acc[r]);
        acc[r] = fmaf(xv.z, wv[j].z, acc[r]);
        acc[r] = fmaf(xv.w, wv[j].w, acc[r]);
      }
    }
  }
}

// ------- initial node kernel: emb gather + inv_node write + 3 node MLPs (layer 0) -------
__global__ __launch_bounds__(128) void k_node3_first(
    const int* __restrict__ z, const float* __restrict__ emb, float* __restrict__ inv_node,
    const float* W1a, const float* b1a, const float* W2a, const float* b2a, float* Ya,
    const float* W1b, const float* b1b, const float* W2b, const float* b2b, float* Yb,
    const float* W1c, const float* b1c, const float* W2c, const float* b2c, float* Yc){
  const float *W1,*b1,*W2,*b2; float* Y;
  if (blockIdx.y==0){ W1=W1a;b1=b1a;W2=W2a;b2=b2a;Y=Ya; }
  else if (blockIdx.y==1){ W1=W1b;b1=b1b;W2=W2b;b2=b2b;Y=Yb; }
  else { W1=W1c;b1=b1c;W2=W2c;b2=b2c;Y=Yc; }
  __shared__ __align__(16) float xs[16][FF];
  __shared__ __align__(16) float hs[16][FF];
  const int o = threadIdx.x;
  const int row0 = blockIdx.x * 16;
  #pragma unroll
  for (int r=0;r<16;++r){
    float v = emb[(size_t)z[row0+r]*FF + o];
    xs[r][o] = v;
    if (blockIdx.y==0) inv_node[(size_t)(row0+r)*FF + o] = v;
  }
  __syncthreads();
  float acc[16];
  mlp16(xs, hs, o, W1, b1, W2, b2, acc);
  #pragma unroll
  for (int r=0;r<16;++r) Y[(size_t)(row0+r)*FF + o] = acc[r];
}

// ---------------- three node MLPs in one dispatch (layers 1,2) ----------------
__global__ __launch_bounds__(128) void k_mlp_node3(const float* __restrict__ X,
    const float* W1a, const float* b1a, const float* W2a, const float* b2a, float* Ya,
    const float* W1b, const float* b1b, const float* W2b, const float* b2b, float* Yb,
    const float* W1c, const float* b1c, const float* W2c, const float* b2c, float* Yc){
  const float *W1,*b1,*W2,*b2; float* Y;
  if (blockIdx.y==0){ W1=W1a;b1=b1a;W2=W2a;b2=b2a;Y=Ya; }
  else if (blockIdx.y==1){ W1=W1b;b1=b1b;W2=W2b;b2=b2b;Y=Yb; }
  else { W1=W1c;b1=b1c;W2=W2c;b2=b2c;Y=Yc; }
  __shared__ __align__(16) float xs[16][FF];
  __shared__ __align__(16) float hs[16][FF];
  const int o = threadIdx.x;
  const int row0 = blockIdx.x * 16;
  #pragma unroll
  for (int r=0;r<16;++r) xs[r][o] = X[(size_t)(row0+r)*FF + o];
  __syncthreads();
  float acc[16];
  mlp16(xs, hs, o, W1, b1, W2, b2, acc);
  #pragma unroll
  for (int r=0;r<16;++r) Y[(size_t)(row0+r)*FF + o] = acc[r];
}

// =====================================================================
// k_layer: merged k_edge1 + k_z. Grid 512, 2 atoms (128 edges) per block.
// Block bid owns atoms 2bid,2bid+1; H1/H2 write-through to global and read
// back by the SAME block (visibility via __syncthreads vmcnt drain).
// Xs reused for inv_msg then all four W stagings. scal/nbq live in LDS.
// =====================================================================
__global__ __launch_bounds__(256) void k_layer(
    const float* __restrict__ dist, const float* __restrict__ dvec,
    const float* __restrict__ maskp, const int* __restrict__ nbrs,
    const float* __restrict__ msg_node,
    const unsigned short* __restrict__ meWb, const float* __restrict__ meb,
    const float* __restrict__ eqcW,
    const unsigned short* __restrict__ W1eq, const float* __restrict__ b1eq,
    const unsigned short* __restrict__ W1me,
    const unsigned short* __restrict__ W2eq, const float* __restrict__ b2eq,
    const unsigned short* __restrict__ W2me,
    unsigned short* __restrict__ H1, unsigned short* __restrict__ H2,
    const float* __restrict__ eqdrT_prev, float* __restrict__ eqdrT_next,
    const float* __restrict__ esu, const float* __restrict__ isu,
    float* __restrict__ eqF, float* __restrict__ eqf_out,
    float* __restrict__ eqdr, float* __restrict__ inv_node, int first){
  __shared__ unsigned short Xs[128*136];      // 34.8 KB (inv_msg, then W stagings)
  __shared__ float scal[128][4];
  __shared__ int   nbq[128];
  __shared__ float eqFred[4][2][3];
  __shared__ float afl1[4][384];
  __shared__ float afl2[4][384];
  __shared__ float prod[2][384];
  const int t = threadIdx.x, w = t>>6, l = t&63;
  const int bid = blockIdx.x, a0 = bid*2;
  const int g = l&15, kg = (l>>4)<<3, r0 = (l>>4)<<2;
  const float c5 = 0.6283185307179586f;      // pi/5

  if (t < 128){
    int e2 = a0*NNB + t;
    int atomt = a0 + (t>>6);
    nbq[t] = (atomt/AA)*AA + nbrs[e2];
  }

  // ---------------- phase A: geometry + me-MLP + inv_msg -> Xs, scal, eqF ----------------
  #pragma unroll
  for (int p=0;p<2;++p){
    const int atom = a0 + p;
    const int eg = atom*NNB + w*16 + g;
    const float d = dist[eg];
    const float dinv = 1.0f/(d + 1e-8f);
    const float xx = d*0.2f;
    float x2=xx*xx, x4=x2*x2, x6=x4*x2, x7=x6*xx, x8=x7*xx;
    float ct = 1.0f - 28.0f*x6 + 48.0f*x7 - 21.0f*x8;
    ct = (xx < 1.0f) ? ct : 0.0f;
    bf16x8 rfr;
    #pragma unroll
    for (int i=0;i<8;++i){
      int k = kg + i;
      float v = (k < NBAS) ? __sinf((float)(k+1)*c5*d)*dinv : 0.0f;
      rfr[i] = (short)f2bf(v);
    }
    f32x4 acc[8];
    #pragma unroll
    for (int nt=0;nt<8;++nt){
      bf16x8 wfr = *(const bf16x8*)(meWb + (nt*16 + g)*32 + kg);
      acc[nt] = __builtin_amdgcn_mfma_f32_16x16x32_bf16(wfr, rfr, f32x4{0.f,0.f,0.f,0.f}, 0,0,0);
    }
    const int bbase = (atom/AA)*AA;
    const int nbv = bbase + nbrs[eg];
    float pv = 0.f;
    #pragma unroll
    for (int nt=0;nt<8;++nt){
      int o0 = nt*16 + r0;
      float4 mb = *(const float4*)(meb + o0);
      float4 mi = *(const float4*)(msg_node + (size_t)atom*FF + o0);
      float4 mf = *(const float4*)(msg_node + (size_t)nbv*FF + o0);
      float4 ec = *(const float4*)(eqcW + o0);
      float v0 = (acc[nt][0]+mb.x)*ct*mi.x*mf.x;
      float v1 = (acc[nt][1]+mb.y)*ct*mi.y*mf.y;
      float v2 = (acc[nt][2]+mb.z)*ct*mi.z*mf.z;
      float v3 = (acc[nt][3]+mb.w)*ct*mi.w*mf.w;
      pv = fmaf(v0,ec.x, fmaf(v1,ec.y, fmaf(v2,ec.z, fmaf(v3,ec.w, pv))));
      uint2 u; u.x = pk2(v0,v1); u.y = pk2(v2,v3);
      *(uint2*)(&Xs[(p*64 + w*16 + g)*136 + o0]) = u;
    }
    pv += __shfl_xor(pv,16); pv += __shfl_xor(pv,32);
    float cf0=0.f, cf1=0.f, cf2=0.f;
    if (l < 16){
      float m  = maskp[eg];
      float s0 = pv*dvec[(size_t)eg*3+0]*dinv;
      float s1 = pv*dvec[(size_t)eg*3+1]*dinv;
      float s2 = pv*dvec[(size_t)eg*3+2]*dinv;
      int lr = p*64 + w*16 + g;
      scal[lr][0]=s0; scal[lr][1]=s1; scal[lr][2]=s2; scal[lr][3]=m;
      cf0 = s0*m; cf1 = s1*m; cf2 = s2*m;
    }
    #pragma unroll
    for (int s2=1; s2<16; s2<<=1){
      cf0 += __shfl_xor(cf0,s2); cf1 += __shfl_xor(cf1,s2); cf2 += __shfl_xor(cf2,s2);
    }
    if (l == 0){ eqFred[w][p][0]=cf0; eqFred[w][p][1]=cf1; eqFred[w][p][2]=cf2; }
  }
  __syncthreads();                           // (1) Xs/scal complete

  // X fragments -> registers; eq_F final write
  bf16x8 xf[2][4];
  #pragma unroll
  for (int ms=0;ms<2;++ms)
    #pragma unroll
    for (int ks=0;ks<4;++ks)
      xf[ms][ks] = *(const bf16x8*)(&Xs[(w*32 + ms*16 + g)*136 + ks*32 + kg]);
  if (t < 6){
    int p = t/3, c = t - p*3;
    float s = eqFred[0][p][c]+eqFred[1][p][c]+eqFred[2][p][c]+eqFred[3][p][c];
    eqF[(a0+p)*3 + c] = first ? s : (eqF[(a0+p)*3 + c] + s);
  }
  __syncthreads();                           // (2) Xs free

  // ---- stage W1eq; GEMM1-eqf -> H1 (global write-through) ----
  #pragma unroll
  for (int c=t; c<2048; c+=256){
    int row = c >> 4, ko = (c & 15) << 3;
    *(int4*)(&Xs[row*136 + ko]) = *(const int4*)(W1eq + row*FF + ko);
  }
  __syncthreads();                           // (3)
  f32x4 acc2[2][8];
  #pragma unroll
  for (int ms=0;ms<2;++ms)
    #pragma unroll
    for (int nt=0;nt<8;++nt) acc2[ms][nt] = f32x4{0.f,0.f,0.f,0.f};
  #pragma unroll
  for (int nt=0;nt<8;++nt)
    #pragma unroll
    for (int ks=0;ks<4;++ks){
      bf16x8 wfr = *(const bf16x8*)(&Xs[(nt*16+g)*136 + ks*32 + kg]);
      #pragma unroll
      for (int ms=0;ms<2;++ms)
        acc2[ms][nt] = __builtin_amdgcn_mfma_f32_16x16x32_bf16(wfr, xf[ms][ks], acc2[ms][nt], 0,0,0);
    }
  #pragma unroll
  for (int ms=0;ms<2;++ms)
    #pragma unroll
    for (int nt=0;nt<8;++nt){
      int o0 = nt*16 + r0;
      float4 bb = *(const float4*)(b1eq + o0);
      uint2 u;
      u.x = pk2(silu_f(acc2[ms][nt][0]+bb.x), silu_f(acc2[ms][nt][1]+bb.y));
      u.y = pk2(silu_f(acc2[ms][nt][2]+bb.z), silu_f(acc2[ms][nt][3]+bb.w));
      *(uint2*)(H1 + (size_t)(bid*128 + w*32 + ms*16 + g)*FF + o0) = u;
    }

  if (!first){
    __syncthreads();                         // (4)
    // ---- stage W1me; GEMM1-eme -> H2 ----
    #pragma unroll
    for (int c=t; c<2048; c+=256){
      int row = c >> 4, ko = (c & 15) << 3;
      *(int4*)(&Xs[row*136 + ko]) = *(const int4*)(W1me + row*FF + ko);
    }
    __syncthreads();                         // (5)
    #pragma unroll
    for (int ms=0;ms<2;++ms)
      #pragma unroll
      for (int nt=0;nt<8;++nt) acc2[ms][nt] = f32x4{0.f,0.f,0.f,0.f};
    #pragma unroll
    for (int nt=0;nt<8;++nt)
      #pragma unroll
      for (int ks=0;ks<4;++ks){
        bf16x8 wfr = *(const bf16x8*)(&Xs[(nt*16+g)*136 + ks*32 + kg]);
        #pragma unroll
        for (int ms=0;ms<2;++ms)
          acc2[ms][nt] = __builtin_amdgcn_mfma_f32_16x16x32_bf16(wfr, xf[ms][ks], acc2[ms][nt], 0,0,0);
      }
    #pragma unroll
    for (int ms=0;ms<2;++ms)
      #pragma unroll
      for (int nt=0;nt<8;++nt){
        int o0 = nt*16 + r0;
        uint2 u;
        u.x = pk2(silu_f(acc2[ms][nt][0]), silu_f(acc2[ms][nt][1]));
        u.y = pk2(silu_f(acc2[ms][nt][2]), silu_f(acc2[ms][nt][3]));
        *(uint2*)(H2 + (size_t)(bid*128 + w*32 + ms*16 + g)*FF + o0) = u;
      }
  }
  __syncthreads();                           // (6) drains H stores; Xs free

  // ================= k_z half =================
  bf16x8 hfr1[2][4];
  #pragma unroll
  for (int ms=0;ms<2;++ms)
    #pragma unroll
    for (int ks=0;ks<4;++ks)
      hfr1[ms][ks] = *(const bf16x8*)(H1 + (size_t)(bid*128 + w*32 + ms*16 + g)*FF + ks*32 + kg);
  // ---- stage W2eq; GEMM2-eqf + masked scal reduce -> afl1 ----
  #pragma unroll
  for (int c=t; c<2048; c+=256){
    int row = c >> 4, ko = (c & 15) << 3;
    *(int4*)(&Xs[row*136 + ko]) = *(const int4*)(W2eq + row*FF + ko);
  }
  __syncthreads();                           // (7)
  f32x4 acc[2][8];
  #pragma unroll
  for (int ms=0;ms<2;++ms)
    #pragma unroll
    for (int nt=0;nt<8;++nt) acc[ms][nt] = f32x4{0.f,0.f,0.f,0.f};
  #pragma unroll
  for (int nt=0;nt<8;++nt)
    #pragma unroll
    for (int ks=0;ks<4;++ks){
      bf16x8 wfr = *(const bf16x8*)(&Xs[(nt*16+g)*136 + ks*32 + kg]);
      #pragma unroll
      for (int ms=0;ms<2;++ms)
        acc[ms][nt] = __builtin_amdgcn_mfma_f32_16x16x32_bf16(hfr1[ms][ks], wfr, acc[ms][nt], 0,0,0);
    }
  #pragma unroll
  for (int nt=0;nt<8;++nt){
    int col = nt*16 + g;
    float bb = b2eq[col];
    float q0=0.f,q1=0.f,q2=0.f;
    #pragma unroll
    for (int ms=0;ms<2;++ms)
      #pragma unroll
      for (int r=0;r<4;++r){
        int row = w*32 + ms*16 + r0 + r;
        float ym = (acc[ms][nt][r] + bb) * scal[row][3];
        q0 = fmaf(ym, scal[row][0], q0);
        q1 = fmaf(ym, scal[row][1], q1);
        q2 = fmaf(ym, scal[row][2], q2);
      }
    q0 += __shfl_xor(q0,16); q0 += __shfl_xor(q0,32);
    q1 += __shfl_xor(q1,16); q1 += __shfl_xor(q1,32);
    q2 += __shfl_xor(q2,16); q2 += __shfl_xor(q2,32);
    if (l < 16){
      afl1[w][0*128+col] = q0; afl1[w][1*128+col] = q1; afl1[w][2*128+col] = q2;
    }
  }
  if (!first){
    bf16x8 hfr2[2][4];
    #pragma unroll
    for (int ms=0;ms<2;++ms)
      #pragma unroll
      for (int ks=0;ks<4;++ks)
        hfr2[ms][ks] = *(const bf16x8*)(H2 + (size_t)(bid*128 + w*32 + ms*16 + g)*FF + ks*32 + kg);
    __syncthreads();                         // (8)
    // ---- stage W2me; GEMM2-eme + eqdrT_prev gather reduce -> afl2 ----
    #pragma unroll
    for (int c=t; c<2048; c+=256){
      int row = c >> 4, ko = (c & 15) << 3;
      *(int4*)(&Xs[row*136 + ko]) = *(const int4*)(W2me + row*FF + ko);
    }
    __syncthreads();                         // (9)
    #pragma unroll
    for (int ms=0;ms<2;++ms)
      #pragma unroll
      for (int nt=0;nt<8;++nt) acc[ms][nt] = f32x4{0.f,0.f,0.f,0.f};
    #pragma unroll
    for (int nt=0;nt<8;++nt)
      #pragma unroll
      for (int ks=0;ks<4;++ks){
        bf16x8 wfr = *(const bf16x8*)(&Xs[(nt*16+g)*136 + ks*32 + kg]);
        #pragma unroll
        for (int ms=0;ms<2;++ms)
          acc[ms][nt] = __builtin_amdgcn_mfma_f32_16x16x32_bf16(hfr2[ms][ks], wfr, acc[ms][nt], 0,0,0);
      }
    #pragma unroll
    for (int nt=0;nt<8;++nt){
      int col = nt*16 + g;
      float q0=0.f,q1=0.f,q2=0.f;
      #pragma unroll
      for (int ms=0;ms<2;++ms)
        #pragma unroll
        for (int r=0;r<4;++r){
          int row = w*32 + ms*16 + r0 + r;
          float ym = acc[ms][nt][r] * scal[row][3];
          float4 gv = *(const float4*)(eqdrT_prev + ((size_t)nbq[row]*FF + col)*4);
          q0 = fmaf(ym, gv.x, q0);
          q1 = fmaf(ym, gv.y, q1);
          q2 = fmaf(ym, gv.z, q2);
        }
      q0 += __shfl_xor(q0,16); q0 += __shfl_xor(q0,32);
      q1 += __shfl_xor(q1,16); q1 += __shfl_xor(q1,32);
      q2 += __shfl_xor(q2,16); q2 += __shfl_xor(q2,32);
      if (l < 16){
        afl2[w][0*128+col] = q0; afl2[w][1*128+col] = q1; afl2[w][2*128+col] = q2;
      }
    }
  }
  __syncthreads();                           // (10)
  // ---- merged finalize for both atoms (768 elems) ----
  for (int i=t; i<768; i+=256){
    int p = (i >= 384) ? 1 : 0;
    int j = i - p*384;
    int o = j & 127;
    int c = j >> 7;
    float s1 = afl1[2*p][j] + afl1[2*p+1][j];
    float s2 = first ? 0.0f : (afl2[2*p][j] + afl2[2*p+1][j]);
    size_t idx = (size_t)(a0+p)*384 + j;
    float ef = first ? s1 : (eqf_out[idx] + s1);
    eqf_out[idx] = ef;
    float es = esu[(size_t)(a0+p)*FF + o];
    float v = (first ? 0.0f : eqdr[idx]) + s2 + es*s1;
    eqdr[idx] = v;
    eqdrT_next[((size_t)(a0+p)*FF + o)*4 + c] = v;
    prod[p][j] = ef * v;
  }
  __syncthreads();
  {
    int p = t >> 7, o = t & 127;
    float sum3 = prod[p][o] + prod[p][128+o] + prod[p][256+o];
    size_t idx = (size_t)(a0+p)*FF + o;
    inv_node[idx] = fmaf(-isu[idx], sum3, inv_node[idx]);
  }
}

extern "C" void kernel_launch(void* const* d_in, const int* in_sizes, int n_in,
                              void* d_out, int out_size, void* d_ws, size_t ws_size,
                              hipStream_t stream){
  const int*   z     = (const int*)  d_in[0];
  const int*   nbrs  = (const int*)  d_in[2];
  const float* maskp = (const float*)d_in[3];
  const float* dist  = (const float*)d_in[4];
  const float* dvec  = (const float*)d_in[5];
  const float* emb   = (const float*)d_in[6];
  const float* me_W  = (const float*)d_in[7];
  const float* me_b  = (const float*)d_in[8];
  const float* mn_W1 = (const float*)d_in[9];
  const float* mn_b1 = (const float*)d_in[10];
  const float* mn_W2 = (const float*)d_in[11];
  const float* mn_b2 = (const float*)d_in[12];
  const float* eqc_W = (const float*)d_in[13];
  const float* eqf_W1= (const float*)d_in[14];
  const float* eqf_b1= (const float*)d_in[15];
  const float* eqf_W2= (const float*)d_in[16];
  const float* eqf_b2= (const float*)d_in[17];
  const float* esu_W1= (const float*)d_in[18];
  const float* esu_b1= (const float*)d_in[19];
  const float* esu_W2= (const float*)d_in[20];
  const float* esu_b2= (const float*)d_in[21];
  const float* eme_W1= (const float*)d_in[22];
  const float* eme_W2= (const float*)d_in[23];
  const float* isu_W1= (const float*)d_in[24];
  const float* isu_b1= (const float*)d_in[25];
  const float* isu_W2= (const float*)d_in[26];
  const float* isu_b2= (const float*)d_in[27];

  float* out      = (float*)d_out;
  float* inv_node = out;                        // BA*FF   = 131072
  float* eqF      = out + 131072;               // BA*3    = 3072
  float* eqf      = out + 134144;               // BA*3*FF = 393216
  float* eqdr     = out + 527360;               // BA*3*FF = 393216

  // workspace layout (floats)
  float* w        = (float*)d_ws;
  float* msg_node = w;                          //   131,072
  float* esu_o    = w + 131072;                 //   131,072
  float* isu_o    = w + 262144;                 //   131,072
  float* eqdrT_A  = w + 393216;                 //   524,288 (BA*FF*4)
  float* eqdrT_B  = w + 917504;                 //   524,288
  unsigned short* wbf = (unsigned short*)(w + 1441792); // 208,896 us
  unsigned short* H1  = (unsigned short*)(w + 1546240); // EDG*FF us
  unsigned short* H2  = (unsigned short*)(w + 5740544); // EDG*FF us

  k_cvtw<<<817, 256, 0, stream>>>(eqf_W1, eqf_W2, eme_W1, eme_W2, me_W, wbf);
  k_node3_first<<<dim3(BA/16, 3), 128, 0, stream>>>(z, emb, inv_node,
      mn_W1,  mn_b1,  mn_W2,  mn_b2,  msg_node,
      esu_W1, esu_b1, esu_W2, esu_b2, esu_o,
      isu_W1, isu_b1, isu_W2, isu_b2, isu_o);

  for (int l=0; l<NLAY; ++l){
    size_t oB = (size_t)l*FF;
    const unsigned short* eqfW1b = wbf + 0*49152 + l*16384;
    const unsigned short* eqfW2b = wbf + 1*49152 + l*16384;
    const unsigned short* emeW1b = wbf + 2*49152 + l*16384;
    const unsigned short* emeW2b = wbf + 3*49152 + l*16384;
    const unsigned short* meWb   = wbf + 196608  + l*4096;
    float* dT_prev = (l & 1) ? eqdrT_B : eqdrT_A;   // unused at l==0 (first)
    float* dT_next = (l & 1) ? eqdrT_A : eqdrT_B;
    int first = (l==0);

    k_layer<<<BA/2, 256, 0, stream>>>(dist, dvec, maskp, nbrs, msg_node,
        meWb, me_b+oB, eqc_W+oB,
        eqfW1b, eqf_b1+oB, emeW1b,
        eqfW2b, eqf_b2+oB, emeW2b,
        H1, H2, dT_prev, dT_next, esu_o, isu_o,
        eqF, eqf, eqdr, inv_node, first);
    if (l < NLAY-1){
      size_t oWn = (size_t)(l+1)*FF*FF, oBn = (size_t)(l+1)*FF;
      k_mlp_node3<<<dim3(BA/16, 3), 128, 0, stream>>>(inv_node,
          mn_W1+oWn,  mn_b1+oBn,  mn_W2+oWn,  mn_b2+oBn,  msg_node,
          esu_W1+oWn, esu_b1+oBn, esu_W2+oWn, esu_b2+oBn, esu_o,
          isu_W1+oWn, isu_b1+oBn, isu_W2+oWn, isu_b2+oBn, isu_o);
    }
  }
}